// Round 3
// baseline (319.336 us; speedup 1.0000x reference)
//
#include <hip/hip_runtime.h>
#include <math.h>

#define N_NODES 50000
#define IN_CH   128
#define TOT_CH  128          // HEADS*OUT_CH
#define NEDGE   800000
#define ETOT    (NEDGE + N_NODES)
#define NEG_SLOPE 0.2f

// ---------------- workspace layout (bytes) ----------------
#define OFF_XL      ((size_t)0)
#define OFF_XR      ((size_t)25600000)          // N*128*4
#define OFF_ROWPTR  ((size_t)51200000)          // (N+1)*4 -> pad
#define OFF_DEG     ((size_t)51400064)
#define OFF_CURSOR  ((size_t)51600064)
#define OFF_SRC     ((size_t)51800064)          // ETOT*4 = 3.4MB

// ================= GEMM: x[N,128] @ [Wl|Wr][128,256] -> xl, xr =================
// block 256 = 4 waves; each wave: 8 rows; lane covers 4 cols of 256 combined.
#define FMA4(a, s, wv4) do { (a).x = fmaf((s),(wv4).x,(a).x); (a).y = fmaf((s),(wv4).y,(a).y); \
                             (a).z = fmaf((s),(wv4).z,(a).z); (a).w = fmaf((s),(wv4).w,(a).w); } while(0)

#define ROWS_PER_WAVE 8

__global__ __launch_bounds__(256) void gemm_kernel(
    const float* __restrict__ x, const float* __restrict__ Wl,
    const float* __restrict__ Wr, float* __restrict__ xl, float* __restrict__ xr)
{
    const int lane = threadIdx.x & 63;
    const int wv   = threadIdx.x >> 6;
    const int rowbase = __builtin_amdgcn_readfirstlane(blockIdx.x * (4 * ROWS_PER_WAVE) + wv * ROWS_PER_WAVE);
    const float* __restrict__ Wbase = (lane < 32) ? Wl : Wr;
    const int col = (lane & 31) * 4;

    float4 acc[ROWS_PER_WAVE];
#pragma unroll
    for (int r = 0; r < ROWS_PER_WAVE; ++r) acc[r] = make_float4(0.f, 0.f, 0.f, 0.f);

#pragma unroll 4
    for (int d4 = 0; d4 < IN_CH; d4 += 4) {
        const float4 w0 = *(const float4*)(Wbase + (size_t)(d4 + 0) * TOT_CH + col);
        const float4 w1 = *(const float4*)(Wbase + (size_t)(d4 + 1) * TOT_CH + col);
        const float4 w2 = *(const float4*)(Wbase + (size_t)(d4 + 2) * TOT_CH + col);
        const float4 w3 = *(const float4*)(Wbase + (size_t)(d4 + 3) * TOT_CH + col);
#pragma unroll
        for (int r = 0; r < ROWS_PER_WAVE; ++r) {
            int row = rowbase + r;
            row = (row < N_NODES) ? row : (N_NODES - 1);
            const float4 xv = *(const float4*)(x + (size_t)row * IN_CH + d4);
            FMA4(acc[r], xv.x, w0);
            FMA4(acc[r], xv.y, w1);
            FMA4(acc[r], xv.z, w2);
            FMA4(acc[r], xv.w, w3);
        }
    }

#pragma unroll
    for (int r = 0; r < ROWS_PER_WAVE; ++r) {
        const int row = rowbase + r;
        if (row < N_NODES) {
            float* dst = (lane < 32) ? (xl + (size_t)row * TOT_CH + col)
                                     : (xr + (size_t)row * TOT_CH + col);
            *(float4*)dst = acc[r];
        }
    }
}

// ================= CSR build =================
__global__ void init_deg_kernel(int* __restrict__ deg) {
    int i = blockIdx.x * 256 + threadIdx.x;
    if (i < N_NODES) deg[i] = 1;   // self loop
}

__global__ void hist_kernel(const int* __restrict__ ei, int* __restrict__ deg) {
    int e = blockIdx.x * 256 + threadIdx.x;
    if (e < NEDGE) atomicAdd(&deg[ei[NEDGE + e]], 1);
}

// chunk-per-thread scan: thread t serially owns deg[t*CHUNK .. t*CHUNK+CHUNK)
#define SCAN_CHUNK ((N_NODES + 1023) / 1024)   // 49
__global__ __launch_bounds__(1024) void scan_kernel(
    const int* __restrict__ deg, int* __restrict__ rowptr, int* __restrict__ cursor)
{
    __shared__ int wsum[16];
    const int tid = threadIdx.x, lane = tid & 63, wid = tid >> 6;
    const int base = tid * SCAN_CHUNK;

    int sum = 0;
#pragma unroll 7
    for (int u = 0; u < SCAN_CHUNK; ++u) {
        const int i = base + u;
        if (i < N_NODES) sum += deg[i];
    }
    int s = sum;
#pragma unroll
    for (int off = 1; off < 64; off <<= 1) {
        int t = __shfl_up(s, off);
        if (lane >= off) s += t;
    }
    if (lane == 63) wsum[wid] = s;
    __syncthreads();
    if (tid == 0) {
        int acc = 0;
#pragma unroll
        for (int w = 0; w < 16; ++w) { int t = wsum[w]; wsum[w] = acc; acc += t; }
    }
    __syncthreads();
    int run = wsum[wid] + s - sum;   // exclusive prefix of this thread's chunk
#pragma unroll 7
    for (int u = 0; u < SCAN_CHUNK; ++u) {
        const int i = base + u;
        if (i < N_NODES) {
            const int v = deg[i];
            cursor[i] = run;
            rowptr[i + 1] = run + v;
            run += v;
        }
    }
    if (tid == 0) rowptr[0] = 0;
}

__global__ void scatter_kernel(const int* __restrict__ ei, int* __restrict__ cursor,
                               int* __restrict__ sorted_src) {
    int e = blockIdx.x * 256 + threadIdx.x;
    if (e >= ETOT) return;
    int src, dst;
    if (e < NEDGE) { src = ei[e]; dst = ei[NEDGE + e]; }
    else           { src = dst = e - NEDGE; }
    int pos = atomicAdd(&cursor[dst], 1);
    sorted_src[pos] = src;
}

// ================= fused attention + aggregate: one wave per dst node =========
// 4-way edge unroll for gather ILP; batched online-softmax update.
__global__ __launch_bounds__(256) void gat_kernel(
    const float* __restrict__ xl, const float* __restrict__ xr,
    const int* __restrict__ rowptr, const int* __restrict__ srcs,
    const float* __restrict__ att, const float* __restrict__ bias,
    float* __restrict__ out)
{
    const int lane = threadIdx.x & 63;
    const int i = blockIdx.x * 4 + (threadIdx.x >> 6);
    if (i >= N_NODES) return;
    const int c = lane * 2;                      // 2 channels per lane; head = lane>>4
    const float2 att2 = *(const float2*)(att + c);
    const float2 xr2  = *(const float2*)(xr + (size_t)i * TOT_CH + c);
    const int k0 = rowptr[i], k1 = rowptr[i + 1];

    float m = -INFINITY, den = 0.f, a0 = 0.f, a1 = 0.f;
    int k = k0;

#define SCORE(v2, sv) do { \
        const float t0 = (v2).x + xr2.x, t1 = (v2).y + xr2.y; \
        const float l0 = fmaxf(t0, 0.f) + NEG_SLOPE * fminf(t0, 0.f); \
        const float l1 = fmaxf(t1, 0.f) + NEG_SLOPE * fminf(t1, 0.f); \
        sv = att2.x * l0 + att2.y * l1; } while(0)

    for (; k + 4 <= k1; k += 4) {
        const int j0 = srcs[k + 0], j1 = srcs[k + 1];
        const int j2 = srcs[k + 2], j3 = srcs[k + 3];
        const float2 v0 = *(const float2*)(xl + (size_t)j0 * TOT_CH + c);
        const float2 v1 = *(const float2*)(xl + (size_t)j1 * TOT_CH + c);
        const float2 v2 = *(const float2*)(xl + (size_t)j2 * TOT_CH + c);
        const float2 v3 = *(const float2*)(xl + (size_t)j3 * TOT_CH + c);
        float s0, s1, s2, s3;
        SCORE(v0, s0); SCORE(v1, s1); SCORE(v2, s2); SCORE(v3, s3);
        // 4 interleaved 16-lane head reductions
        s0 += __shfl_xor(s0, 1); s1 += __shfl_xor(s1, 1); s2 += __shfl_xor(s2, 1); s3 += __shfl_xor(s3, 1);
        s0 += __shfl_xor(s0, 2); s1 += __shfl_xor(s1, 2); s2 += __shfl_xor(s2, 2); s3 += __shfl_xor(s3, 2);
        s0 += __shfl_xor(s0, 4); s1 += __shfl_xor(s1, 4); s2 += __shfl_xor(s2, 4); s3 += __shfl_xor(s3, 4);
        s0 += __shfl_xor(s0, 8); s1 += __shfl_xor(s1, 8); s2 += __shfl_xor(s2, 8); s3 += __shfl_xor(s3, 8);
        const float mx = fmaxf(fmaxf(fmaxf(s0, s1), fmaxf(s2, s3)), m);
        const float corr = __expf(m - mx);
        const float p0 = __expf(s0 - mx), p1 = __expf(s1 - mx);
        const float p2 = __expf(s2 - mx), p3 = __expf(s3 - mx);
        den = den * corr + ((p0 + p1) + (p2 + p3));
        a0  = a0  * corr + ((p0 * v0.x + p1 * v1.x) + (p2 * v2.x + p3 * v3.x));
        a1  = a1  * corr + ((p0 * v0.y + p1 * v1.y) + (p2 * v2.y + p3 * v3.y));
        m = mx;
    }
    for (; k < k1; ++k) {
        const int j = srcs[k];
        const float2 v = *(const float2*)(xl + (size_t)j * TOT_CH + c);
        float s;
        SCORE(v, s);
        s += __shfl_xor(s, 1);
        s += __shfl_xor(s, 2);
        s += __shfl_xor(s, 4);
        s += __shfl_xor(s, 8);
        const float mn   = fmaxf(m, s);
        const float corr = __expf(m - mn);
        const float p    = __expf(s - mn);
        den = den * corr + p;
        a0  = a0 * corr + p * v.x;
        a1  = a1 * corr + p * v.y;
        m = mn;
    }
    const float inv = 1.f / den;
    const float2 b2 = *(const float2*)(bias + c);
    float2 o;
    o.x = a0 * inv + b2.x;
    o.y = a1 * inv + b2.y;
    *(float2*)(out + (size_t)i * TOT_CH + c) = o;
}

// ================= launch =================
extern "C" void kernel_launch(void* const* d_in, const int* in_sizes, int n_in,
                              void* d_out, int out_size, void* d_ws, size_t ws_size,
                              hipStream_t stream) {
    const float* x    = (const float*)d_in[0];
    const int*   ei   = (const int*)d_in[1];
    const float* Wl   = (const float*)d_in[2];
    const float* Wr   = (const float*)d_in[3];
    const float* att  = (const float*)d_in[4];
    const float* bias = (const float*)d_in[5];
    float* out = (float*)d_out;
    char*  ws  = (char*)d_ws;

    float* xl     = (float*)(ws + OFF_XL);
    float* xr     = (float*)(ws + OFF_XR);
    int*   rowptr = (int*)(ws + OFF_ROWPTR);
    int*   deg    = (int*)(ws + OFF_DEG);
    int*   cursor = (int*)(ws + OFF_CURSOR);
    int*   ssrc   = (int*)(ws + OFF_SRC);

    hipLaunchKernelGGL(gemm_kernel, dim3((N_NODES + 4 * ROWS_PER_WAVE - 1) / (4 * ROWS_PER_WAVE)),
                       dim3(256), 0, stream, x, Wl, Wr, xl, xr);
    hipLaunchKernelGGL(init_deg_kernel, dim3((N_NODES + 255) / 256), dim3(256), 0, stream, deg);
    hipLaunchKernelGGL(hist_kernel, dim3((NEDGE + 255) / 256), dim3(256), 0, stream, ei, deg);
    hipLaunchKernelGGL(scan_kernel, dim3(1), dim3(1024), 0, stream, deg, rowptr, cursor);
    hipLaunchKernelGGL(scatter_kernel, dim3((ETOT + 255) / 256), dim3(256), 0, stream,
                       ei, cursor, ssrc);
    hipLaunchKernelGGL(gat_kernel, dim3((N_NODES + 3) / 4), dim3(256), 0, stream,
                       xl, xr, rowptr, ssrc, att, bias, out);
}

// Round 4
// 205.252 us; speedup vs baseline: 1.5558x; 1.5558x over previous
//
#include <hip/hip_runtime.h>
#include <math.h>

#define N_NODES 50000
#define IN_CH   128
#define TOT_CH  128          // HEADS*OUT_CH
#define NEDGE   800000
#define ETOT    (NEDGE + N_NODES)
#define NEG_SLOPE 0.2f
#define NB_SCAN ((N_NODES + 255) / 256)   // 196 scan blocks

// ---------------- workspace layout (bytes) ----------------
#define OFF_XL      ((size_t)0)
#define OFF_XR      ((size_t)25600000)          // N*128*4
#define OFF_ROWPTR  ((size_t)51200000)          // (N+1)*4 -> pad
#define OFF_DEG     ((size_t)51400064)
#define OFF_CURSOR  ((size_t)51600064)
#define OFF_SRC     ((size_t)51800064)          // ETOT*4 = 3.4MB
#define OFF_BSUM    ((size_t)55200064)
#define OFF_BPRE    ((size_t)55202112)

// ================= GEMM: x[N,128] @ [Wl|Wr][128,256] -> xl, xr =================
#define FMA4(a, s, wv4) do { (a).x = fmaf((s),(wv4).x,(a).x); (a).y = fmaf((s),(wv4).y,(a).y); \
                             (a).z = fmaf((s),(wv4).z,(a).z); (a).w = fmaf((s),(wv4).w,(a).w); } while(0)

#define ROWS_PER_WAVE 8

__global__ __launch_bounds__(256) void gemm_kernel(
    const float* __restrict__ x, const float* __restrict__ Wl,
    const float* __restrict__ Wr, float* __restrict__ xl, float* __restrict__ xr)
{
    const int lane = threadIdx.x & 63;
    const int wv   = threadIdx.x >> 6;
    const int rowbase = __builtin_amdgcn_readfirstlane(blockIdx.x * (4 * ROWS_PER_WAVE) + wv * ROWS_PER_WAVE);
    const float* __restrict__ Wbase = (lane < 32) ? Wl : Wr;
    const int col = (lane & 31) * 4;

    float4 acc[ROWS_PER_WAVE];
#pragma unroll
    for (int r = 0; r < ROWS_PER_WAVE; ++r) acc[r] = make_float4(0.f, 0.f, 0.f, 0.f);

#pragma unroll 4
    for (int d4 = 0; d4 < IN_CH; d4 += 4) {
        const float4 w0 = *(const float4*)(Wbase + (size_t)(d4 + 0) * TOT_CH + col);
        const float4 w1 = *(const float4*)(Wbase + (size_t)(d4 + 1) * TOT_CH + col);
        const float4 w2 = *(const float4*)(Wbase + (size_t)(d4 + 2) * TOT_CH + col);
        const float4 w3 = *(const float4*)(Wbase + (size_t)(d4 + 3) * TOT_CH + col);
#pragma unroll
        for (int r = 0; r < ROWS_PER_WAVE; ++r) {
            int row = rowbase + r;
            row = (row < N_NODES) ? row : (N_NODES - 1);
            const float4 xv = *(const float4*)(x + (size_t)row * IN_CH + d4);
            FMA4(acc[r], xv.x, w0);
            FMA4(acc[r], xv.y, w1);
            FMA4(acc[r], xv.z, w2);
            FMA4(acc[r], xv.w, w3);
        }
    }

#pragma unroll
    for (int r = 0; r < ROWS_PER_WAVE; ++r) {
        const int row = rowbase + r;
        if (row < N_NODES) {
            float* dst = (lane < 32) ? (xl + (size_t)row * TOT_CH + col)
                                     : (xr + (size_t)row * TOT_CH + col);
            *(float4*)dst = acc[r];
        }
    }
}

// ================= CSR build =================
__global__ void init_deg_kernel(int* __restrict__ deg) {
    int i = blockIdx.x * 256 + threadIdx.x;
    if (i < N_NODES) deg[i] = 1;   // self loop
}

__global__ void hist_kernel(const int* __restrict__ ei, int* __restrict__ deg) {
    int e = blockIdx.x * 256 + threadIdx.x;
    if (e < NEDGE) atomicAdd(&deg[ei[NEDGE + e]], 1);
}

// ---- hierarchical scan: block sums -> scan partials -> emit ----
__global__ __launch_bounds__(256) void block_sum_kernel(
    const int* __restrict__ deg, int* __restrict__ bsum)
{
    __shared__ int wsum[4];
    const int tid = threadIdx.x, lane = tid & 63, wid = tid >> 6;
    const int i = blockIdx.x * 256 + tid;
    int v = (i < N_NODES) ? deg[i] : 0;
#pragma unroll
    for (int off = 32; off >= 1; off >>= 1) v += __shfl_xor(v, off);
    if (lane == 0) wsum[wid] = v;
    __syncthreads();
    if (tid == 0) bsum[blockIdx.x] = wsum[0] + wsum[1] + wsum[2] + wsum[3];
}

__global__ __launch_bounds__(256) void scan_partials_kernel(
    const int* __restrict__ bsum, int* __restrict__ bpre)
{
    __shared__ int wsum[4];
    const int tid = threadIdx.x, lane = tid & 63, wid = tid >> 6;
    const int v = (tid < NB_SCAN) ? bsum[tid] : 0;
    int s = v;
#pragma unroll
    for (int off = 1; off < 64; off <<= 1) {
        int t = __shfl_up(s, off);
        if (lane >= off) s += t;
    }
    if (lane == 63) wsum[wid] = s;
    __syncthreads();
    if (tid == 0) {
        int acc = 0;
#pragma unroll
        for (int w = 0; w < 4; ++w) { int t = wsum[w]; wsum[w] = acc; acc += t; }
    }
    __syncthreads();
    if (tid < NB_SCAN) bpre[tid] = wsum[wid] + s - v;   // exclusive
}

__global__ __launch_bounds__(256) void emit_kernel(
    const int* __restrict__ deg, const int* __restrict__ bpre,
    int* __restrict__ rowptr, int* __restrict__ cursor)
{
    __shared__ int wsum[4];
    const int tid = threadIdx.x, lane = tid & 63, wid = tid >> 6;
    const int i = blockIdx.x * 256 + tid;
    const int v = (i < N_NODES) ? deg[i] : 0;
    int s = v;
#pragma unroll
    for (int off = 1; off < 64; off <<= 1) {
        int t = __shfl_up(s, off);
        if (lane >= off) s += t;
    }
    if (lane == 63) wsum[wid] = s;
    __syncthreads();
    if (tid == 0) {
        int acc = 0;
#pragma unroll
        for (int w = 0; w < 4; ++w) { int t = wsum[w]; wsum[w] = acc; acc += t; }
    }
    __syncthreads();
    if (i < N_NODES) {
        const int excl = bpre[blockIdx.x] + wsum[wid] + s - v;
        cursor[i] = excl;
        rowptr[i + 1] = excl + v;
        if (i == 0) rowptr[0] = 0;
    }
}

__global__ void scatter_kernel(const int* __restrict__ ei, int* __restrict__ cursor,
                               int* __restrict__ sorted_src) {
    int e = blockIdx.x * 256 + threadIdx.x;
    if (e >= ETOT) return;
    int src, dst;
    if (e < NEDGE) { src = ei[e]; dst = ei[NEDGE + e]; }
    else           { src = dst = e - NEDGE; }
    int pos = atomicAdd(&cursor[dst], 1);
    sorted_src[pos] = src;
}

// ================= fused attention + aggregate: one wave per dst node =========
__global__ __launch_bounds__(256) void gat_kernel(
    const float* __restrict__ xl, const float* __restrict__ xr,
    const int* __restrict__ rowptr, const int* __restrict__ srcs,
    const float* __restrict__ att, const float* __restrict__ bias,
    float* __restrict__ out)
{
    const int lane = threadIdx.x & 63;
    const int i = blockIdx.x * 4 + (threadIdx.x >> 6);
    if (i >= N_NODES) return;
    const int c = lane * 2;                      // 2 channels per lane; head = lane>>4
    const float2 att2 = *(const float2*)(att + c);
    const float2 xr2  = *(const float2*)(xr + (size_t)i * TOT_CH + c);
    const int k0 = rowptr[i], k1 = rowptr[i + 1];

    float m = -INFINITY, den = 0.f, a0 = 0.f, a1 = 0.f;
    int k = k0;

#define SCORE(v2, sv) do { \
        const float t0 = (v2).x + xr2.x, t1 = (v2).y + xr2.y; \
        const float l0 = fmaxf(t0, 0.f) + NEG_SLOPE * fminf(t0, 0.f); \
        const float l1 = fmaxf(t1, 0.f) + NEG_SLOPE * fminf(t1, 0.f); \
        sv = att2.x * l0 + att2.y * l1; } while(0)

    for (; k + 4 <= k1; k += 4) {
        const int j0 = srcs[k + 0], j1 = srcs[k + 1];
        const int j2 = srcs[k + 2], j3 = srcs[k + 3];
        const float2 v0 = *(const float2*)(xl + (size_t)j0 * TOT_CH + c);
        const float2 v1 = *(const float2*)(xl + (size_t)j1 * TOT_CH + c);
        const float2 v2 = *(const float2*)(xl + (size_t)j2 * TOT_CH + c);
        const float2 v3 = *(const float2*)(xl + (size_t)j3 * TOT_CH + c);
        float s0, s1, s2, s3;
        SCORE(v0, s0); SCORE(v1, s1); SCORE(v2, s2); SCORE(v3, s3);
        s0 += __shfl_xor(s0, 1); s1 += __shfl_xor(s1, 1); s2 += __shfl_xor(s2, 1); s3 += __shfl_xor(s3, 1);
        s0 += __shfl_xor(s0, 2); s1 += __shfl_xor(s1, 2); s2 += __shfl_xor(s2, 2); s3 += __shfl_xor(s3, 2);
        s0 += __shfl_xor(s0, 4); s1 += __shfl_xor(s1, 4); s2 += __shfl_xor(s2, 4); s3 += __shfl_xor(s3, 4);
        s0 += __shfl_xor(s0, 8); s1 += __shfl_xor(s1, 8); s2 += __shfl_xor(s2, 8); s3 += __shfl_xor(s3, 8);
        const float mx = fmaxf(fmaxf(fmaxf(s0, s1), fmaxf(s2, s3)), m);
        const float corr = __expf(m - mx);
        const float p0 = __expf(s0 - mx), p1 = __expf(s1 - mx);
        const float p2 = __expf(s2 - mx), p3 = __expf(s3 - mx);
        den = den * corr + ((p0 + p1) + (p2 + p3));
        a0  = a0  * corr + ((p0 * v0.x + p1 * v1.x) + (p2 * v2.x + p3 * v3.x));
        a1  = a1  * corr + ((p0 * v0.y + p1 * v1.y) + (p2 * v2.y + p3 * v3.y));
        m = mx;
    }
    for (; k < k1; ++k) {
        const int j = srcs[k];
        const float2 v = *(const float2*)(xl + (size_t)j * TOT_CH + c);
        float s;
        SCORE(v, s);
        s += __shfl_xor(s, 1);
        s += __shfl_xor(s, 2);
        s += __shfl_xor(s, 4);
        s += __shfl_xor(s, 8);
        const float mn   = fmaxf(m, s);
        const float corr = __expf(m - mn);
        const float p    = __expf(s - mn);
        den = den * corr + p;
        a0  = a0 * corr + p * v.x;
        a1  = a1 * corr + p * v.y;
        m = mn;
    }
    const float inv = 1.f / den;
    const float2 b2 = *(const float2*)(bias + c);
    float2 o;
    o.x = a0 * inv + b2.x;
    o.y = a1 * inv + b2.y;
    *(float2*)(out + (size_t)i * TOT_CH + c) = o;
}

// ================= launch =================
extern "C" void kernel_launch(void* const* d_in, const int* in_sizes, int n_in,
                              void* d_out, int out_size, void* d_ws, size_t ws_size,
                              hipStream_t stream) {
    const float* x    = (const float*)d_in[0];
    const int*   ei   = (const int*)d_in[1];
    const float* Wl   = (const float*)d_in[2];
    const float* Wr   = (const float*)d_in[3];
    const float* att  = (const float*)d_in[4];
    const float* bias = (const float*)d_in[5];
    float* out = (float*)d_out;
    char*  ws  = (char*)d_ws;

    float* xl     = (float*)(ws + OFF_XL);
    float* xr     = (float*)(ws + OFF_XR);
    int*   rowptr = (int*)(ws + OFF_ROWPTR);
    int*   deg    = (int*)(ws + OFF_DEG);
    int*   cursor = (int*)(ws + OFF_CURSOR);
    int*   ssrc   = (int*)(ws + OFF_SRC);
    int*   bsum   = (int*)(ws + OFF_BSUM);
    int*   bpre   = (int*)(ws + OFF_BPRE);

    hipLaunchKernelGGL(gemm_kernel, dim3((N_NODES + 4 * ROWS_PER_WAVE - 1) / (4 * ROWS_PER_WAVE)),
                       dim3(256), 0, stream, x, Wl, Wr, xl, xr);
    hipLaunchKernelGGL(init_deg_kernel, dim3((N_NODES + 255) / 256), dim3(256), 0, stream, deg);
    hipLaunchKernelGGL(hist_kernel, dim3((NEDGE + 255) / 256), dim3(256), 0, stream, ei, deg);
    hipLaunchKernelGGL(block_sum_kernel, dim3(NB_SCAN), dim3(256), 0, stream, deg, bsum);
    hipLaunchKernelGGL(scan_partials_kernel, dim3(1), dim3(256), 0, stream, bsum, bpre);
    hipLaunchKernelGGL(emit_kernel, dim3(NB_SCAN), dim3(256), 0, stream, deg, bpre, rowptr, cursor);
    hipLaunchKernelGGL(scatter_kernel, dim3((ETOT + 255) / 256), dim3(256), 0, stream,
                       ei, cursor, ssrc);
    hipLaunchKernelGGL(gat_kernel, dim3((N_NODES + 3) / 4), dim3(256), 0, stream,
                       xl, xr, rowptr, ssrc, att, bias, out);
}

// Round 5
// 202.665 us; speedup vs baseline: 1.5757x; 1.0128x over previous
//
#include <hip/hip_runtime.h>
#include <math.h>

#define N_NODES 50000
#define IN_CH   128
#define TOT_CH  128          // HEADS*OUT_CH
#define NEDGE   800000
#define ETOT    (NEDGE + N_NODES)
#define NEG_SLOPE 0.2f
#define NB_SCAN ((N_NODES + 255) / 256)   // 196 scan blocks

// ---------------- workspace layout (bytes) ----------------
#define OFF_XL      ((size_t)0)                 // bf16 [N][128] = 12.8MB
#define OFF_XR      ((size_t)25600000)          // f32  [N][128]
#define OFF_ROWPTR  ((size_t)51200000)
#define OFF_DEG     ((size_t)51400064)
#define OFF_CURSOR  ((size_t)51600064)
#define OFF_SRC     ((size_t)51800064)
#define OFF_BSUM    ((size_t)55200064)
#define OFF_BPRE    ((size_t)55202112)

__device__ __forceinline__ unsigned f2bf(float f) {   // RNE f32->bf16 bits
    unsigned u = __float_as_uint(f);
    return (u + 0x7fffu + ((u >> 16) & 1u)) >> 16;
}
__device__ __forceinline__ float bflo(unsigned u) { return __uint_as_float(u << 16); }
__device__ __forceinline__ float bfhi(unsigned u) { return __uint_as_float(u & 0xffff0000u); }

// ================= GEMM: x[N,128] @ [Wl|Wr][128,256] -> xl(bf16), xr(f32) =====
#define FMA4(a, s, wv4) do { (a).x = fmaf((s),(wv4).x,(a).x); (a).y = fmaf((s),(wv4).y,(a).y); \
                             (a).z = fmaf((s),(wv4).z,(a).z); (a).w = fmaf((s),(wv4).w,(a).w); } while(0)

#define ROWS_PER_WAVE 8

__global__ __launch_bounds__(256) void gemm_kernel(
    const float* __restrict__ x, const float* __restrict__ Wl,
    const float* __restrict__ Wr, unsigned* __restrict__ xl_bf, float* __restrict__ xr)
{
    const int lane = threadIdx.x & 63;
    const int wv   = threadIdx.x >> 6;
    const int rowbase = __builtin_amdgcn_readfirstlane(blockIdx.x * (4 * ROWS_PER_WAVE) + wv * ROWS_PER_WAVE);
    const float* __restrict__ Wbase = (lane < 32) ? Wl : Wr;
    const int col = (lane & 31) * 4;

    float4 acc[ROWS_PER_WAVE];
#pragma unroll
    for (int r = 0; r < ROWS_PER_WAVE; ++r) acc[r] = make_float4(0.f, 0.f, 0.f, 0.f);

#pragma unroll 4
    for (int d4 = 0; d4 < IN_CH; d4 += 4) {
        const float4 w0 = *(const float4*)(Wbase + (size_t)(d4 + 0) * TOT_CH + col);
        const float4 w1 = *(const float4*)(Wbase + (size_t)(d4 + 1) * TOT_CH + col);
        const float4 w2 = *(const float4*)(Wbase + (size_t)(d4 + 2) * TOT_CH + col);
        const float4 w3 = *(const float4*)(Wbase + (size_t)(d4 + 3) * TOT_CH + col);
#pragma unroll
        for (int r = 0; r < ROWS_PER_WAVE; ++r) {
            int row = rowbase + r;
            row = (row < N_NODES) ? row : (N_NODES - 1);
            const float4 xv = *(const float4*)(x + (size_t)row * IN_CH + d4);
            FMA4(acc[r], xv.x, w0);
            FMA4(acc[r], xv.y, w1);
            FMA4(acc[r], xv.z, w2);
            FMA4(acc[r], xv.w, w3);
        }
    }

#pragma unroll
    for (int r = 0; r < ROWS_PER_WAVE; ++r) {
        const int row = rowbase + r;
        if (row < N_NODES) {
            if (lane < 32) {   // xl in bf16: 2 uints = 4 channels
                uint2 p;
                p.x = f2bf(acc[r].x) | (f2bf(acc[r].y) << 16);
                p.y = f2bf(acc[r].z) | (f2bf(acc[r].w) << 16);
                *(uint2*)(xl_bf + (size_t)row * 64 + (lane & 31) * 2) = p;
            } else {
                *(float4*)(xr + (size_t)row * TOT_CH + col) = acc[r];
            }
        }
    }
}

// ================= CSR build =================
__global__ void init_deg_kernel(int* __restrict__ deg) {
    int i = blockIdx.x * 256 + threadIdx.x;
    if (i < N_NODES) deg[i] = 1;   // self loop
}

__global__ void hist_kernel(const int* __restrict__ ei, int* __restrict__ deg) {
    int e = blockIdx.x * 256 + threadIdx.x;
    if (e < NEDGE) atomicAdd(&deg[ei[NEDGE + e]], 1);
}

__global__ __launch_bounds__(256) void block_sum_kernel(
    const int* __restrict__ deg, int* __restrict__ bsum)
{
    __shared__ int wsum[4];
    const int tid = threadIdx.x, lane = tid & 63, wid = tid >> 6;
    const int i = blockIdx.x * 256 + tid;
    int v = (i < N_NODES) ? deg[i] : 0;
#pragma unroll
    for (int off = 32; off >= 1; off >>= 1) v += __shfl_xor(v, off);
    if (lane == 0) wsum[wid] = v;
    __syncthreads();
    if (tid == 0) bsum[blockIdx.x] = wsum[0] + wsum[1] + wsum[2] + wsum[3];
}

__global__ __launch_bounds__(256) void scan_partials_kernel(
    const int* __restrict__ bsum, int* __restrict__ bpre)
{
    __shared__ int wsum[4];
    const int tid = threadIdx.x, lane = tid & 63, wid = tid >> 6;
    const int v = (tid < NB_SCAN) ? bsum[tid] : 0;
    int s = v;
#pragma unroll
    for (int off = 1; off < 64; off <<= 1) {
        int t = __shfl_up(s, off);
        if (lane >= off) s += t;
    }
    if (lane == 63) wsum[wid] = s;
    __syncthreads();
    if (tid == 0) {
        int acc = 0;
#pragma unroll
        for (int w = 0; w < 4; ++w) { int t = wsum[w]; wsum[w] = acc; acc += t; }
    }
    __syncthreads();
    if (tid < NB_SCAN) bpre[tid] = wsum[wid] + s - v;   // exclusive
}

__global__ __launch_bounds__(256) void emit_kernel(
    const int* __restrict__ deg, const int* __restrict__ bpre,
    int* __restrict__ rowptr, int* __restrict__ cursor)
{
    __shared__ int wsum[4];
    const int tid = threadIdx.x, lane = tid & 63, wid = tid >> 6;
    const int i = blockIdx.x * 256 + tid;
    const int v = (i < N_NODES) ? deg[i] : 0;
    int s = v;
#pragma unroll
    for (int off = 1; off < 64; off <<= 1) {
        int t = __shfl_up(s, off);
        if (lane >= off) s += t;
    }
    if (lane == 63) wsum[wid] = s;
    __syncthreads();
    if (tid == 0) {
        int acc = 0;
#pragma unroll
        for (int w = 0; w < 4; ++w) { int t = wsum[w]; wsum[w] = acc; acc += t; }
    }
    __syncthreads();
    if (i < N_NODES) {
        const int excl = bpre[blockIdx.x] + wsum[wid] + s - v;
        cursor[i] = excl;
        rowptr[i + 1] = excl + v;
        if (i == 0) rowptr[0] = 0;
    }
}

__global__ void scatter_kernel(const int* __restrict__ ei, int* __restrict__ cursor,
                               int* __restrict__ sorted_src) {
    int e = blockIdx.x * 256 + threadIdx.x;
    if (e >= ETOT) return;
    int src, dst;
    if (e < NEDGE) { src = ei[e]; dst = ei[NEDGE + e]; }
    else           { src = dst = e - NEDGE; }
    int pos = atomicAdd(&cursor[dst], 1);
    sorted_src[pos] = src;
}

// ================= fused attention + aggregate: one wave per dst node =========
__global__ __launch_bounds__(256) void gat_kernel(
    const unsigned* __restrict__ xl_bf, const float* __restrict__ xr,
    const int* __restrict__ rowptr, const int* __restrict__ srcs,
    const float* __restrict__ att, const float* __restrict__ bias,
    float* __restrict__ out)
{
    const int lane = threadIdx.x & 63;
    const int i = blockIdx.x * 4 + (threadIdx.x >> 6);
    if (i >= N_NODES) return;
    const int c = lane * 2;                      // 2 channels per lane; head = lane>>4
    const float2 att2 = *(const float2*)(att + c);
    const float2 xr2  = *(const float2*)(xr + (size_t)i * TOT_CH + c);
    const int k0 = rowptr[i], k1 = rowptr[i + 1];

    float m = -INFINITY, den = 0.f, a0 = 0.f, a1 = 0.f;
    int k = k0;

#define SCOREU(u, sv) do { \
        const float t0 = bflo(u) + xr2.x, t1 = bfhi(u) + xr2.y; \
        const float l0 = fmaxf(t0, 0.f) + NEG_SLOPE * fminf(t0, 0.f); \
        const float l1 = fmaxf(t1, 0.f) + NEG_SLOPE * fminf(t1, 0.f); \
        sv = att2.x * l0 + att2.y * l1; } while(0)

#define RED4(a, b, cc, d) do { \
        a += __shfl_xor(a, 1); b += __shfl_xor(b, 1); cc += __shfl_xor(cc, 1); d += __shfl_xor(d, 1); \
        a += __shfl_xor(a, 2); b += __shfl_xor(b, 2); cc += __shfl_xor(cc, 2); d += __shfl_xor(d, 2); \
        a += __shfl_xor(a, 4); b += __shfl_xor(b, 4); cc += __shfl_xor(cc, 4); d += __shfl_xor(d, 4); \
        a += __shfl_xor(a, 8); b += __shfl_xor(b, 8); cc += __shfl_xor(cc, 8); d += __shfl_xor(d, 8); } while(0)

    for (; k + 8 <= k1; k += 8) {
        const int j0 = srcs[k + 0], j1 = srcs[k + 1], j2 = srcs[k + 2], j3 = srcs[k + 3];
        const int j4 = srcs[k + 4], j5 = srcs[k + 5], j6 = srcs[k + 6], j7 = srcs[k + 7];
        const unsigned u0 = xl_bf[(size_t)j0 * 64 + lane];
        const unsigned u1 = xl_bf[(size_t)j1 * 64 + lane];
        const unsigned u2 = xl_bf[(size_t)j2 * 64 + lane];
        const unsigned u3 = xl_bf[(size_t)j3 * 64 + lane];
        const unsigned u4 = xl_bf[(size_t)j4 * 64 + lane];
        const unsigned u5 = xl_bf[(size_t)j5 * 64 + lane];
        const unsigned u6 = xl_bf[(size_t)j6 * 64 + lane];
        const unsigned u7 = xl_bf[(size_t)j7 * 64 + lane];
        float s0, s1, s2, s3, s4, s5, s6, s7;
        SCOREU(u0, s0); SCOREU(u1, s1); SCOREU(u2, s2); SCOREU(u3, s3);
        SCOREU(u4, s4); SCOREU(u5, s5); SCOREU(u6, s6); SCOREU(u7, s7);
        RED4(s0, s1, s2, s3);
        RED4(s4, s5, s6, s7);
        const float mx = fmaxf(fmaxf(fmaxf(fmaxf(s0, s1), fmaxf(s2, s3)),
                                     fmaxf(fmaxf(s4, s5), fmaxf(s6, s7))), m);
        const float corr = __expf(m - mx);
        const float p0 = __expf(s0 - mx), p1 = __expf(s1 - mx);
        const float p2 = __expf(s2 - mx), p3 = __expf(s3 - mx);
        const float p4 = __expf(s4 - mx), p5 = __expf(s5 - mx);
        const float p6 = __expf(s6 - mx), p7 = __expf(s7 - mx);
        den = den * corr + (((p0 + p1) + (p2 + p3)) + ((p4 + p5) + (p6 + p7)));
        a0  = a0  * corr + (((p0 * bflo(u0) + p1 * bflo(u1)) + (p2 * bflo(u2) + p3 * bflo(u3)))
                          + ((p4 * bflo(u4) + p5 * bflo(u5)) + (p6 * bflo(u6) + p7 * bflo(u7))));
        a1  = a1  * corr + (((p0 * bfhi(u0) + p1 * bfhi(u1)) + (p2 * bfhi(u2) + p3 * bfhi(u3)))
                          + ((p4 * bfhi(u4) + p5 * bfhi(u5)) + (p6 * bfhi(u6) + p7 * bfhi(u7))));
        m = mx;
    }
    for (; k + 4 <= k1; k += 4) {
        const int j0 = srcs[k + 0], j1 = srcs[k + 1], j2 = srcs[k + 2], j3 = srcs[k + 3];
        const unsigned u0 = xl_bf[(size_t)j0 * 64 + lane];
        const unsigned u1 = xl_bf[(size_t)j1 * 64 + lane];
        const unsigned u2 = xl_bf[(size_t)j2 * 64 + lane];
        const unsigned u3 = xl_bf[(size_t)j3 * 64 + lane];
        float s0, s1, s2, s3;
        SCOREU(u0, s0); SCOREU(u1, s1); SCOREU(u2, s2); SCOREU(u3, s3);
        RED4(s0, s1, s2, s3);
        const float mx = fmaxf(fmaxf(fmaxf(s0, s1), fmaxf(s2, s3)), m);
        const float corr = __expf(m - mx);
        const float p0 = __expf(s0 - mx), p1 = __expf(s1 - mx);
        const float p2 = __expf(s2 - mx), p3 = __expf(s3 - mx);
        den = den * corr + ((p0 + p1) + (p2 + p3));
        a0  = a0  * corr + ((p0 * bflo(u0) + p1 * bflo(u1)) + (p2 * bflo(u2) + p3 * bflo(u3)));
        a1  = a1  * corr + ((p0 * bfhi(u0) + p1 * bfhi(u1)) + (p2 * bfhi(u2) + p3 * bfhi(u3)));
        m = mx;
    }
    for (; k < k1; ++k) {
        const int j = srcs[k];
        const unsigned u = xl_bf[(size_t)j * 64 + lane];
        float s;
        SCOREU(u, s);
        s += __shfl_xor(s, 1);
        s += __shfl_xor(s, 2);
        s += __shfl_xor(s, 4);
        s += __shfl_xor(s, 8);
        const float mn   = fmaxf(m, s);
        const float corr = __expf(m - mn);
        const float p    = __expf(s - mn);
        den = den * corr + p;
        a0  = a0 * corr + p * bflo(u);
        a1  = a1 * corr + p * bfhi(u);
        m = mn;
    }
    const float inv = 1.f / den;
    const float2 b2 = *(const float2*)(bias + c);
    float2 o;
    o.x = a0 * inv + b2.x;
    o.y = a1 * inv + b2.y;
    *(float2*)(out + (size_t)i * TOT_CH + c) = o;
}

// ================= launch =================
extern "C" void kernel_launch(void* const* d_in, const int* in_sizes, int n_in,
                              void* d_out, int out_size, void* d_ws, size_t ws_size,
                              hipStream_t stream) {
    const float* x    = (const float*)d_in[0];
    const int*   ei   = (const int*)d_in[1];
    const float* Wl   = (const float*)d_in[2];
    const float* Wr   = (const float*)d_in[3];
    const float* att  = (const float*)d_in[4];
    const float* bias = (const float*)d_in[5];
    float* out = (float*)d_out;
    char*  ws  = (char*)d_ws;

    unsigned* xl_bf = (unsigned*)(ws + OFF_XL);
    float*    xr    = (float*)(ws + OFF_XR);
    int*   rowptr = (int*)(ws + OFF_ROWPTR);
    int*   deg    = (int*)(ws + OFF_DEG);
    int*   cursor = (int*)(ws + OFF_CURSOR);
    int*   ssrc   = (int*)(ws + OFF_SRC);
    int*   bsum   = (int*)(ws + OFF_BSUM);
    int*   bpre   = (int*)(ws + OFF_BPRE);

    hipLaunchKernelGGL(gemm_kernel, dim3((N_NODES + 4 * ROWS_PER_WAVE - 1) / (4 * ROWS_PER_WAVE)),
                       dim3(256), 0, stream, x, Wl, Wr, xl_bf, xr);
    hipLaunchKernelGGL(init_deg_kernel, dim3((N_NODES + 255) / 256), dim3(256), 0, stream, deg);
    hipLaunchKernelGGL(hist_kernel, dim3((NEDGE + 255) / 256), dim3(256), 0, stream, ei, deg);
    hipLaunchKernelGGL(block_sum_kernel, dim3(NB_SCAN), dim3(256), 0, stream, deg, bsum);
    hipLaunchKernelGGL(scan_partials_kernel, dim3(1), dim3(256), 0, stream, bsum, bpre);
    hipLaunchKernelGGL(emit_kernel, dim3(NB_SCAN), dim3(256), 0, stream, deg, bpre, rowptr, cursor);
    hipLaunchKernelGGL(scatter_kernel, dim3((ETOT + 255) / 256), dim3(256), 0, stream,
                       ei, cursor, ssrc);
    hipLaunchKernelGGL(gat_kernel, dim3((N_NODES + 3) / 4), dim3(256), 0, stream,
                       xl_bf, xr, rowptr, ssrc, att, bias, out);
}

// Round 6
// 176.657 us; speedup vs baseline: 1.8077x; 1.1472x over previous
//
#include <hip/hip_runtime.h>
#include <math.h>

#define N_NODES 50000
#define IN_CH   128
#define TOT_CH  128          // HEADS*OUT_CH
#define NEDGE   800000
#define ETOT    (NEDGE + N_NODES)
#define NEG_SLOPE 0.2f
#define NB_SCAN ((N_NODES + 255) / 256)   // 196 scan blocks
#define MTILES  ((N_NODES + 63) / 64)     // 782

// ---------------- workspace layout (bytes) ----------------
#define OFF_XL      ((size_t)0)                 // bf16 [N][128] = 12.8MB
#define OFF_XR      ((size_t)25600000)          // f32  [N][128]
#define OFF_ROWPTR  ((size_t)51200000)
#define OFF_DEG     ((size_t)51400064)          // also overlaid by BT during gemm
#define OFF_CURSOR  ((size_t)51600064)
#define OFF_SRC     ((size_t)51800064)
#define OFF_BSUM    ((size_t)55200064)
#define OFF_BPRE    ((size_t)55202112)
#define OFF_BT      OFF_DEG                     // Bt[256][128] bf16 = 64KB; dead before init_deg

typedef float f32x4 __attribute__((ext_vector_type(4)));
typedef short s16x8 __attribute__((ext_vector_type(8)));

__device__ __forceinline__ unsigned f2bf(float f) {   // RNE f32->bf16 bits
    unsigned u = __float_as_uint(f);
    return (u + 0x7fffu + ((u >> 16) & 1u)) >> 16;
}
__device__ __forceinline__ float bflo(unsigned u) { return __uint_as_float(u << 16); }
__device__ __forceinline__ float bfhi(unsigned u) { return __uint_as_float(u & 0xffff0000u); }

// LDS tile byte-offset with T2-style XOR swizzle (16B granular within 8-row stripes)
__device__ __forceinline__ int SWZ(int row, int byteoff) {
    return row * 256 + (byteoff ^ ((row & 7) << 4));
}

// ============ W conversion: [Wl|Wr] f32 [k][n] -> Bt bf16-pairs [n][k/2] ============
__global__ __launch_bounds__(256) void wconv_kernel(
    const float* __restrict__ Wl, const float* __restrict__ Wr, unsigned* __restrict__ btg)
{
    const int g = blockIdx.x * 256 + threadIdx.x;   // 256*64 = 16384 u32s
    if (g >= 256 * 64) return;
    const int n = g >> 6, kk = g & 63;
    const float* W = (n < 128) ? Wl : Wr;
    const int nc = n & 127;
    const float a = W[(size_t)(2 * kk) * 128 + nc];
    const float b = W[(size_t)(2 * kk + 1) * 128 + nc];
    btg[g] = f2bf(a) | (f2bf(b) << 16);
}

// ============ MFMA GEMM: x[N,128](f32->bf16) @ Bt -> xl(bf16), xr(f32) ============
// grid = MTILES*4; nt = bid/MTILES (n-major for L2 locality), mt = bid%MTILES.
// block 256 = 4 waves; block computes 64(m) x 64(n); K=128 single shot.
__global__ __launch_bounds__(256) void gemm_kernel(
    const float* __restrict__ x, const unsigned* __restrict__ btg,
    unsigned* __restrict__ xl_bf, float* __restrict__ xr)
{
    __shared__ __align__(16) unsigned char Al[64 * 256];   // 64 rows x 128 bf16
    __shared__ __align__(16) unsigned char Bl[64 * 256];

    const int t  = threadIdx.x;
    const int nt = blockIdx.x / MTILES;
    const int mt = blockIdx.x % MTILES;
    const int mbase = mt * 64;
    const int nbase = nt * 64;

    // ---- stage A (f32 -> bf16, swizzled) ----
    {
        const int r = t >> 2, q = t & 3;
        int gm = mbase + r;
        gm = (gm < N_NODES) ? gm : (N_NODES - 1);
        const float* xrow = x + (size_t)gm * IN_CH + q * 32;
#pragma unroll
        for (int i = 0; i < 8; ++i) {
            const float4 xv = *(const float4*)(xrow + i * 4);
            uint2 p;
            p.x = f2bf(xv.x) | (f2bf(xv.y) << 16);
            p.y = f2bf(xv.z) | (f2bf(xv.w) << 16);
            *(uint2*)(Al + SWZ(r, q * 64 + i * 8)) = p;
        }
    }
    // ---- stage B (already bf16, swizzled) ----
    {
        const int r = t >> 2, q = t & 3;
        const unsigned* brow = btg + (size_t)(nbase + r) * 64 + q * 16;
#pragma unroll
        for (int i = 0; i < 4; ++i) {
            const uint4 v = *(const uint4*)(brow + i * 4);
            *(uint4*)(Bl + SWZ(r, q * 64 + i * 16)) = v;
        }
    }
    __syncthreads();

    const int l  = t & 63;
    const int wv = t >> 6;

    f32x4 acc[4];
#pragma unroll
    for (int n = 0; n < 4; ++n) acc[n] = (f32x4){0.f, 0.f, 0.f, 0.f};

    s16x8 af[4];
#pragma unroll
    for (int ks = 0; ks < 4; ++ks)
        af[ks] = *(const s16x8*)(Al + SWZ(wv * 16 + (l & 15), ks * 64 + (l >> 4) * 16));

#pragma unroll
    for (int nsub = 0; nsub < 4; ++nsub) {
#pragma unroll
        for (int ks = 0; ks < 4; ++ks) {
            const s16x8 bfr = *(const s16x8*)(Bl + SWZ(nsub * 16 + (l & 15), ks * 64 + (l >> 4) * 16));
            acc[nsub] = __builtin_amdgcn_mfma_f32_16x16x32_bf16(af[ks], bfr, acc[nsub], 0, 0, 0);
        }
    }

    // ---- epilogue: C/D map col=lane&15, row=(lane>>4)*4+reg (m89-verified) ----
    if (nt < 2) {   // all 64 n-cols of this block belong to xl (bf16, u32-paired)
#pragma unroll
        for (int nsub = 0; nsub < 4; ++nsub) {
            const int n = nt * 64 + nsub * 16 + (l & 15);
#pragma unroll
            for (int reg = 0; reg < 4; ++reg) {
                const float v  = acc[nsub][reg];
                const float vp = __shfl_xor(v, 1);
                const int row = mbase + wv * 16 + (l >> 4) * 4 + reg;
                if (((l & 1) == 0) && row < N_NODES)
                    xl_bf[(size_t)row * 64 + (n >> 1)] = f2bf(v) | (f2bf(vp) << 16);
            }
        }
    } else {        // xr (f32)
#pragma unroll
        for (int nsub = 0; nsub < 4; ++nsub) {
            const int cx = (nt - 2) * 64 + nsub * 16 + (l & 15);
#pragma unroll
            for (int reg = 0; reg < 4; ++reg) {
                const int row = mbase + wv * 16 + (l >> 4) * 4 + reg;
                if (row < N_NODES)
                    xr[(size_t)row * TOT_CH + cx] = acc[nsub][reg];
            }
        }
    }
}

// ================= CSR build =================
__global__ void init_deg_kernel(int* __restrict__ deg) {
    int i = blockIdx.x * 256 + threadIdx.x;
    if (i < N_NODES) deg[i] = 1;   // self loop
}

__global__ void hist_kernel(const int* __restrict__ ei, int* __restrict__ deg) {
    int e = blockIdx.x * 256 + threadIdx.x;
    if (e < NEDGE) atomicAdd(&deg[ei[NEDGE + e]], 1);
}

__global__ __launch_bounds__(256) void block_sum_kernel(
    const int* __restrict__ deg, int* __restrict__ bsum)
{
    __shared__ int wsum[4];
    const int tid = threadIdx.x, lane = tid & 63, wid = tid >> 6;
    const int i = blockIdx.x * 256 + tid;
    int v = (i < N_NODES) ? deg[i] : 0;
#pragma unroll
    for (int off = 32; off >= 1; off >>= 1) v += __shfl_xor(v, off);
    if (lane == 0) wsum[wid] = v;
    __syncthreads();
    if (tid == 0) bsum[blockIdx.x] = wsum[0] + wsum[1] + wsum[2] + wsum[3];
}

__global__ __launch_bounds__(256) void scan_partials_kernel(
    const int* __restrict__ bsum, int* __restrict__ bpre)
{
    __shared__ int wsum[4];
    const int tid = threadIdx.x, lane = tid & 63, wid = tid >> 6;
    const int v = (tid < NB_SCAN) ? bsum[tid] : 0;
    int s = v;
#pragma unroll
    for (int off = 1; off < 64; off <<= 1) {
        int t = __shfl_up(s, off);
        if (lane >= off) s += t;
    }
    if (lane == 63) wsum[wid] = s;
    __syncthreads();
    if (tid == 0) {
        int acc = 0;
#pragma unroll
        for (int w = 0; w < 4; ++w) { int t = wsum[w]; wsum[w] = acc; acc += t; }
    }
    __syncthreads();
    if (tid < NB_SCAN) bpre[tid] = wsum[wid] + s - v;   // exclusive
}

__global__ __launch_bounds__(256) void emit_kernel(
    const int* __restrict__ deg, const int* __restrict__ bpre,
    int* __restrict__ rowptr, int* __restrict__ cursor)
{
    __shared__ int wsum[4];
    const int tid = threadIdx.x, lane = tid & 63, wid = tid >> 6;
    const int i = blockIdx.x * 256 + tid;
    const int v = (i < N_NODES) ? deg[i] : 0;
    int s = v;
#pragma unroll
    for (int off = 1; off < 64; off <<= 1) {
        int t = __shfl_up(s, off);
        if (lane >= off) s += t;
    }
    if (lane == 63) wsum[wid] = s;
    __syncthreads();
    if (tid == 0) {
        int acc = 0;
#pragma unroll
        for (int w = 0; w < 4; ++w) { int t = wsum[w]; wsum[w] = acc; acc += t; }
    }
    __syncthreads();
    if (i < N_NODES) {
        const int excl = bpre[blockIdx.x] + wsum[wid] + s - v;
        cursor[i] = excl;
        rowptr[i + 1] = excl + v;
        if (i == 0) rowptr[0] = 0;
    }
}

__global__ void scatter_kernel(const int* __restrict__ ei, int* __restrict__ cursor,
                               int* __restrict__ sorted_src) {
    int e = blockIdx.x * 256 + threadIdx.x;
    if (e >= ETOT) return;
    int src, dst;
    if (e < NEDGE) { src = ei[e]; dst = ei[NEDGE + e]; }
    else           { src = dst = e - NEDGE; }
    int pos = atomicAdd(&cursor[dst], 1);
    sorted_src[pos] = src;
}

// ================= fused attention + aggregate: one wave per dst node =========
__global__ __launch_bounds__(256) void gat_kernel(
    const unsigned* __restrict__ xl_bf, const float* __restrict__ xr,
    const int* __restrict__ rowptr, const int* __restrict__ srcs,
    const float* __restrict__ att, const float* __restrict__ bias,
    float* __restrict__ out)
{
    const int lane = threadIdx.x & 63;
    const int i = blockIdx.x * 4 + (threadIdx.x >> 6);
    if (i >= N_NODES) return;
    const int c = lane * 2;                      // 2 channels per lane; head = lane>>4
    const float2 att2 = *(const float2*)(att + c);
    const float2 xr2  = *(const float2*)(xr + (size_t)i * TOT_CH + c);
    const int k0 = rowptr[i], k1 = rowptr[i + 1];

    float m = -INFINITY, den = 0.f, a0 = 0.f, a1 = 0.f;
    int k = k0;

#define SCOREU(u, sv) do { \
        const float t0 = bflo(u) + xr2.x, t1 = bfhi(u) + xr2.y; \
        const float l0 = fmaxf(t0, 0.f) + NEG_SLOPE * fminf(t0, 0.f); \
        const float l1 = fmaxf(t1, 0.f) + NEG_SLOPE * fminf(t1, 0.f); \
        sv = att2.x * l0 + att2.y * l1; } while(0)

#define RED4(a, b, cc, d) do { \
        a += __shfl_xor(a, 1); b += __shfl_xor(b, 1); cc += __shfl_xor(cc, 1); d += __shfl_xor(d, 1); \
        a += __shfl_xor(a, 2); b += __shfl_xor(b, 2); cc += __shfl_xor(cc, 2); d += __shfl_xor(d, 2); \
        a += __shfl_xor(a, 4); b += __shfl_xor(b, 4); cc += __shfl_xor(cc, 4); d += __shfl_xor(d, 4); \
        a += __shfl_xor(a, 8); b += __shfl_xor(b, 8); cc += __shfl_xor(cc, 8); d += __shfl_xor(d, 8); } while(0)

    for (; k + 8 <= k1; k += 8) {
        const int j0 = srcs[k + 0], j1 = srcs[k + 1], j2 = srcs[k + 2], j3 = srcs[k + 3];
        const int j4 = srcs[k + 4], j5 = srcs[k + 5], j6 = srcs[k + 6], j7 = srcs[k + 7];
        const unsigned u0 = xl_bf[(size_t)j0 * 64 + lane];
        const unsigned u1 = xl_bf[(size_t)j1 * 64 + lane];
        const unsigned u2 = xl_bf[(size_t)j2 * 64 + lane];
        const unsigned u3 = xl_bf[(size_t)j3 * 64 + lane];
        const unsigned u4 = xl_bf[(size_t)j4 * 64 + lane];
        const unsigned u5 = xl_bf[(size_t)j5 * 64 + lane];
        const unsigned u6 = xl_bf[(size_t)j6 * 64 + lane];
        const unsigned u7 = xl_bf[(size_t)j7 * 64 + lane];
        float s0, s1, s2, s3, s4, s5, s6, s7;
        SCOREU(u0, s0); SCOREU(u1, s1); SCOREU(u2, s2); SCOREU(u3, s3);
        SCOREU(u4, s4); SCOREU(u5, s5); SCOREU(u6, s6); SCOREU(u7, s7);
        RED4(s0, s1, s2, s3);
        RED4(s4, s5, s6, s7);
        const float mx = fmaxf(fmaxf(fmaxf(fmaxf(s0, s1), fmaxf(s2, s3)),
                                     fmaxf(fmaxf(s4, s5), fmaxf(s6, s7))), m);
        const float corr = __expf(m - mx);
        const float p0 = __expf(s0 - mx), p1 = __expf(s1 - mx);
        const float p2 = __expf(s2 - mx), p3 = __expf(s3 - mx);
        const float p4 = __expf(s4 - mx), p5 = __expf(s5 - mx);
        const float p6 = __expf(s6 - mx), p7 = __expf(s7 - mx);
        den = den * corr + (((p0 + p1) + (p2 + p3)) + ((p4 + p5) + (p6 + p7)));
        a0  = a0  * corr + (((p0 * bflo(u0) + p1 * bflo(u1)) + (p2 * bflo(u2) + p3 * bflo(u3)))
                          + ((p4 * bflo(u4) + p5 * bflo(u5)) + (p6 * bflo(u6) + p7 * bflo(u7))));
        a1  = a1  * corr + (((p0 * bfhi(u0) + p1 * bfhi(u1)) + (p2 * bfhi(u2) + p3 * bfhi(u3)))
                          + ((p4 * bfhi(u4) + p5 * bfhi(u5)) + (p6 * bfhi(u6) + p7 * bfhi(u7))));
        m = mx;
    }
    for (; k + 4 <= k1; k += 4) {
        const int j0 = srcs[k + 0], j1 = srcs[k + 1], j2 = srcs[k + 2], j3 = srcs[k + 3];
        const unsigned u0 = xl_bf[(size_t)j0 * 64 + lane];
        const unsigned u1 = xl_bf[(size_t)j1 * 64 + lane];
        const unsigned u2 = xl_bf[(size_t)j2 * 64 + lane];
        const unsigned u3 = xl_bf[(size_t)j3 * 64 + lane];
        float s0, s1, s2, s3;
        SCOREU(u0, s0); SCOREU(u1, s1); SCOREU(u2, s2); SCOREU(u3, s3);
        RED4(s0, s1, s2, s3);
        const float mx = fmaxf(fmaxf(fmaxf(s0, s1), fmaxf(s2, s3)), m);
        const float corr = __expf(m - mx);
        const float p0 = __expf(s0 - mx), p1 = __expf(s1 - mx);
        const float p2 = __expf(s2 - mx), p3 = __expf(s3 - mx);
        den = den * corr + ((p0 + p1) + (p2 + p3));
        a0  = a0  * corr + ((p0 * bflo(u0) + p1 * bflo(u1)) + (p2 * bflo(u2) + p3 * bflo(u3)));
        a1  = a1  * corr + ((p0 * bfhi(u0) + p1 * bfhi(u1)) + (p2 * bfhi(u2) + p3 * bfhi(u3)));
        m = mx;
    }
    for (; k < k1; ++k) {
        const int j = srcs[k];
        const unsigned u = xl_bf[(size_t)j * 64 + lane];
        float s;
        SCOREU(u, s);
        s += __shfl_xor(s, 1);
        s += __shfl_xor(s, 2);
        s += __shfl_xor(s, 4);
        s += __shfl_xor(s, 8);
        const float mn   = fmaxf(m, s);
        const float corr = __expf(m - mn);
        const float p    = __expf(s - mn);
        den = den * corr + p;
        a0  = a0 * corr + p * bflo(u);
        a1  = a1 * corr + p * bfhi(u);
        m = mn;
    }
    const float inv = 1.f / den;
    const float2 b2 = *(const float2*)(bias + c);
    float2 o;
    o.x = a0 * inv + b2.x;
    o.y = a1 * inv + b2.y;
    *(float2*)(out + (size_t)i * TOT_CH + c) = o;
}

// ================= launch =================
extern "C" void kernel_launch(void* const* d_in, const int* in_sizes, int n_in,
                              void* d_out, int out_size, void* d_ws, size_t ws_size,
                              hipStream_t stream) {
    const float* x    = (const float*)d_in[0];
    const int*   ei   = (const int*)d_in[1];
    const float* Wl   = (const float*)d_in[2];
    const float* Wr   = (const float*)d_in[3];
    const float* att  = (const float*)d_in[4];
    const float* bias = (const float*)d_in[5];
    float* out = (float*)d_out;
    char*  ws  = (char*)d_ws;

    unsigned* xl_bf = (unsigned*)(ws + OFF_XL);
    float*    xr    = (float*)(ws + OFF_XR);
    int*   rowptr = (int*)(ws + OFF_ROWPTR);
    int*   deg    = (int*)(ws + OFF_DEG);
    int*   cursor = (int*)(ws + OFF_CURSOR);
    int*   ssrc   = (int*)(ws + OFF_SRC);
    int*   bsum   = (int*)(ws + OFF_BSUM);
    int*   bpre   = (int*)(ws + OFF_BPRE);
    unsigned* btg = (unsigned*)(ws + OFF_BT);   // overlaid on deg; dead before init_deg

    hipLaunchKernelGGL(wconv_kernel, dim3(64), dim3(256), 0, stream, Wl, Wr, btg);
    hipLaunchKernelGGL(gemm_kernel, dim3(MTILES * 4), dim3(256), 0, stream,
                       x, btg, xl_bf, xr);
    hipLaunchKernelGGL(init_deg_kernel, dim3((N_NODES + 255) / 256), dim3(256), 0, stream, deg);
    hipLaunchKernelGGL(hist_kernel, dim3((NEDGE + 255) / 256), dim3(256), 0, stream, ei, deg);
    hipLaunchKernelGGL(block_sum_kernel, dim3(NB_SCAN), dim3(256), 0, stream, deg, bsum);
    hipLaunchKernelGGL(scan_partials_kernel, dim3(1), dim3(256), 0, stream, bsum, bpre);
    hipLaunchKernelGGL(emit_kernel, dim3(NB_SCAN), dim3(256), 0, stream, deg, bpre, rowptr, cursor);
    hipLaunchKernelGGL(scatter_kernel, dim3((ETOT + 255) / 256), dim3(256), 0, stream,
                       ei, cursor, ssrc);
    hipLaunchKernelGGL(gat_kernel, dim3((N_NODES + 3) / 4), dim3(256), 0, stream,
                       xl_bf, xr, rowptr, ssrc, att, bias, out);
}

// Round 7
// 119.555 us; speedup vs baseline: 2.6710x; 1.4776x over previous
//
#include <hip/hip_runtime.h>
#include <math.h>

#define N_NODES 50000
#define IN_CH   128
#define TOT_CH  128          // HEADS*OUT_CH
#define NEDGE   800000
#define ETOT    (NEDGE + N_NODES)
#define NEG_SLOPE 0.2f
#define MTILES  ((N_NODES + 63) / 64)     // 782
#define BUCK_SHIFT 8
#define NBUCK   ((N_NODES + 255) / 256)   // 196 buckets of 256 nodes
#define EPB     4096                       // edges per binning block
#define NBIN    ((ETOT + EPB - 1) / EPB)   // 208

// ---------------- workspace layout (bytes) ----------------
#define OFF_XL      ((size_t)0)                 // bf16 [N][128] = 12.8MB
#define OFF_EBUF    ((size_t)12800000)          // uint2 [ETOT] = 6.8MB (gap before XR)
#define OFF_XR      ((size_t)25600000)          // f32  [N][128] = 25.6MB
#define OFF_ROWPTR  ((size_t)51200000)          // (N+1)*4
#define OFF_BT      ((size_t)51400064)          // Bt bf16-pairs 64KB
#define OFF_SRC     ((size_t)51800064)          // ETOT*4 = 3.4MB
#define OFF_GCNT    ((size_t)55200064)
#define OFF_BSTART  ((size_t)55201088)
#define OFF_GCUR    ((size_t)55202112)

typedef float f32x4 __attribute__((ext_vector_type(4)));
typedef short s16x8 __attribute__((ext_vector_type(8)));

__device__ __forceinline__ unsigned f2bf(float f) {   // RNE f32->bf16 bits
    unsigned u = __float_as_uint(f);
    return (u + 0x7fffu + ((u >> 16) & 1u)) >> 16;
}
__device__ __forceinline__ float bflo(unsigned u) { return __uint_as_float(u << 16); }
__device__ __forceinline__ float bfhi(unsigned u) { return __uint_as_float(u & 0xffff0000u); }

__device__ __forceinline__ int SWZ(int row, int byteoff) {
    return row * 256 + (byteoff ^ ((row & 7) << 4));
}

// ============ W conversion + gcnt zero ============
__global__ __launch_bounds__(256) void wconv_kernel(
    const float* __restrict__ Wl, const float* __restrict__ Wr,
    unsigned* __restrict__ btg, int* __restrict__ gcnt)
{
    const int g = blockIdx.x * 256 + threadIdx.x;
    if (g < NBUCK) gcnt[g] = 0;
    if (g >= 256 * 64) return;
    const int n = g >> 6, kk = g & 63;
    const float* W = (n < 128) ? Wl : Wr;
    const int nc = n & 127;
    const float a = W[(size_t)(2 * kk) * 128 + nc];
    const float b = W[(size_t)(2 * kk + 1) * 128 + nc];
    btg[g] = f2bf(a) | (f2bf(b) << 16);
}

// ============ MFMA GEMM: x[N,128](f32->bf16) @ Bt -> xl(bf16), xr(f32) ============
__global__ __launch_bounds__(256) void gemm_kernel(
    const float* __restrict__ x, const unsigned* __restrict__ btg,
    unsigned* __restrict__ xl_bf, float* __restrict__ xr)
{
    __shared__ __align__(16) unsigned char Al[64 * 256];
    __shared__ __align__(16) unsigned char Bl[64 * 256];

    const int t  = threadIdx.x;
    const int nt = blockIdx.x / MTILES;
    const int mt = blockIdx.x % MTILES;
    const int mbase = mt * 64;
    const int nbase = nt * 64;

    {
        const int r = t >> 2, q = t & 3;
        int gm = mbase + r;
        gm = (gm < N_NODES) ? gm : (N_NODES - 1);
        const float* xrow = x + (size_t)gm * IN_CH + q * 32;
#pragma unroll
        for (int i = 0; i < 8; ++i) {
            const float4 xv = *(const float4*)(xrow + i * 4);
            uint2 p;
            p.x = f2bf(xv.x) | (f2bf(xv.y) << 16);
            p.y = f2bf(xv.z) | (f2bf(xv.w) << 16);
            *(uint2*)(Al + SWZ(r, q * 64 + i * 8)) = p;
        }
    }
    {
        const int r = t >> 2, q = t & 3;
        const unsigned* brow = btg + (size_t)(nbase + r) * 64 + q * 16;
#pragma unroll
        for (int i = 0; i < 4; ++i) {
            const uint4 v = *(const uint4*)(brow + i * 4);
            *(uint4*)(Bl + SWZ(r, q * 64 + i * 16)) = v;
        }
    }
    __syncthreads();

    const int l  = t & 63;
    const int wv = t >> 6;

    f32x4 acc[4];
#pragma unroll
    for (int n = 0; n < 4; ++n) acc[n] = (f32x4){0.f, 0.f, 0.f, 0.f};

    s16x8 af[4];
#pragma unroll
    for (int ks = 0; ks < 4; ++ks)
        af[ks] = *(const s16x8*)(Al + SWZ(wv * 16 + (l & 15), ks * 64 + (l >> 4) * 16));

#pragma unroll
    for (int nsub = 0; nsub < 4; ++nsub) {
#pragma unroll
        for (int ks = 0; ks < 4; ++ks) {
            const s16x8 bfr = *(const s16x8*)(Bl + SWZ(nsub * 16 + (l & 15), ks * 64 + (l >> 4) * 16));
            acc[nsub] = __builtin_amdgcn_mfma_f32_16x16x32_bf16(af[ks], bfr, acc[nsub], 0, 0, 0);
        }
    }

    if (nt < 2) {
#pragma unroll
        for (int nsub = 0; nsub < 4; ++nsub) {
            const int n = nt * 64 + nsub * 16 + (l & 15);
#pragma unroll
            for (int reg = 0; reg < 4; ++reg) {
                const float v  = acc[nsub][reg];
                const float vp = __shfl_xor(v, 1);
                const int row = mbase + wv * 16 + (l >> 4) * 4 + reg;
                if (((l & 1) == 0) && row < N_NODES)
                    xl_bf[(size_t)row * 64 + (n >> 1)] = f2bf(v) | (f2bf(vp) << 16);
            }
        }
    } else {
#pragma unroll
        for (int nsub = 0; nsub < 4; ++nsub) {
            const int cx = (nt - 2) * 64 + nsub * 16 + (l & 15);
#pragma unroll
            for (int reg = 0; reg < 4; ++reg) {
                const int row = mbase + wv * 16 + (l >> 4) * 4 + reg;
                if (row < N_NODES)
                    xr[(size_t)row * TOT_CH + cx] = acc[nsub][reg];
            }
        }
    }
}

// ================= CSR build via bucketed counting sort =================
__global__ __launch_bounds__(256) void binA_kernel(
    const int* __restrict__ ei, int* __restrict__ gcnt)
{
    __shared__ int lcnt[NBUCK];
    for (int i = threadIdx.x; i < NBUCK; i += 256) lcnt[i] = 0;
    __syncthreads();
    const int base = blockIdx.x * EPB;
#pragma unroll
    for (int u = 0; u < 16; ++u) {
        const int e = base + u * 256 + threadIdx.x;
        if (e < ETOT) {
            const int dst = (e < NEDGE) ? ei[NEDGE + e] : (e - NEDGE);
            atomicAdd(&lcnt[dst >> BUCK_SHIFT], 1);
        }
    }
    __syncthreads();
    for (int i = threadIdx.x; i < NBUCK; i += 256) {
        const int v = lcnt[i];
        if (v) atomicAdd(&gcnt[i], v);
    }
}

__global__ __launch_bounds__(256) void scanB_kernel(
    const int* __restrict__ gcnt, int* __restrict__ bstart,
    int* __restrict__ gcursor, int* __restrict__ rowptr)
{
    __shared__ int wsum[4];
    const int tid = threadIdx.x, lane = tid & 63, wid = tid >> 6;
    const int v = (tid < NBUCK) ? gcnt[tid] : 0;
    int s = v;
#pragma unroll
    for (int off = 1; off < 64; off <<= 1) {
        int t = __shfl_up(s, off);
        if (lane >= off) s += t;
    }
    if (lane == 63) wsum[wid] = s;
    __syncthreads();
    if (tid == 0) {
        int acc = 0;
#pragma unroll
        for (int w = 0; w < 4; ++w) { int t = wsum[w]; wsum[w] = acc; acc += t; }
    }
    __syncthreads();
    if (tid < NBUCK) {
        const int e = wsum[wid] + s - v;
        bstart[tid] = e;
        gcursor[tid] = e;
    }
    if (tid == 0) rowptr[N_NODES] = ETOT;
}

__global__ __launch_bounds__(256) void binscatter_kernel(
    const int* __restrict__ ei, int* __restrict__ gcursor, uint2* __restrict__ ebuf)
{
    __shared__ int lcnt[NBUCK];
    __shared__ int lbase[NBUCK];
    for (int i = threadIdx.x; i < NBUCK; i += 256) lcnt[i] = 0;
    __syncthreads();
    const int base = blockIdx.x * EPB;
    int srcv[16], dstv[16];
#pragma unroll
    for (int u = 0; u < 16; ++u) {
        const int e = base + u * 256 + threadIdx.x;
        int s32 = 0, d32 = -1;
        if (e < ETOT) {
            if (e < NEDGE) { s32 = ei[e]; d32 = ei[NEDGE + e]; }
            else           { s32 = d32 = e - NEDGE; }
            atomicAdd(&lcnt[d32 >> BUCK_SHIFT], 1);
        }
        srcv[u] = s32; dstv[u] = d32;
    }
    __syncthreads();
    for (int i = threadIdx.x; i < NBUCK; i += 256) {
        const int v = lcnt[i];
        lbase[i] = v ? atomicAdd(&gcursor[i], v) : 0;
    }
    __syncthreads();
    for (int i = threadIdx.x; i < NBUCK; i += 256) lcnt[i] = 0;
    __syncthreads();
#pragma unroll
    for (int u = 0; u < 16; ++u) {
        const int d32 = dstv[u];
        if (d32 >= 0) {
            const int b = d32 >> BUCK_SHIFT;
            const int p = lbase[b] + atomicAdd(&lcnt[b], 1);
            ebuf[p] = make_uint2((unsigned)srcv[u], (unsigned)d32);
        }
    }
}

// one block per bucket: derive rowptr for 256 nodes + place srcs (LDS atomics only)
__global__ __launch_bounds__(512) void place_kernel(
    const uint2* __restrict__ ebuf, const int* __restrict__ gcnt,
    const int* __restrict__ bstart, int* __restrict__ rowptr, int* __restrict__ ssrc)
{
    __shared__ int lcnt[256];
    __shared__ int wsum[4];
    const int b = blockIdx.x;
    const int node0 = b << BUCK_SHIFT;
    const int estart = bstart[b];
    const int ecnt = gcnt[b];
    const int tid = threadIdx.x, lane = tid & 63, wid = tid >> 6;
    if (tid < 256) lcnt[tid] = 0;
    __syncthreads();
    for (int k = tid; k < ecnt; k += 512) {
        const uint2 ed = ebuf[estart + k];
        atomicAdd(&lcnt[ed.y & 255], 1);
    }
    __syncthreads();
    int v = 0, s = 0;
    if (tid < 256) {
        v = lcnt[tid];
        s = v;
#pragma unroll
        for (int off = 1; off < 64; off <<= 1) {
            int t = __shfl_up(s, off);
            if (lane >= off) s += t;
        }
        if (lane == 63) wsum[wid] = s;
    }
    __syncthreads();
    if (tid == 0) {
        int acc = 0;
#pragma unroll
        for (int w = 0; w < 4; ++w) { int t = wsum[w]; wsum[w] = acc; acc += t; }
    }
    __syncthreads();
    if (tid < 256) {
        const int gpos = estart + wsum[wid] + s - v;   // exclusive prefix
        const int node = node0 + tid;
        if (node < N_NODES) rowptr[node] = gpos;
        lcnt[tid] = gpos;                               // reuse as cursor
    }
    __syncthreads();
    for (int k = tid; k < ecnt; k += 512) {
        const uint2 ed = ebuf[estart + k];
        const int p = atomicAdd(&lcnt[ed.y & 255], 1);
        ssrc[p] = (int)ed.x;
    }
}

// ================= fused attention + aggregate: one wave per dst node =========
__global__ __launch_bounds__(256) void gat_kernel(
    const unsigned* __restrict__ xl_bf, const float* __restrict__ xr,
    const int* __restrict__ rowptr, const int* __restrict__ srcs,
    const float* __restrict__ att, const float* __restrict__ bias,
    float* __restrict__ out)
{
    const int lane = threadIdx.x & 63;
    const int i = blockIdx.x * 4 + (threadIdx.x >> 6);
    if (i >= N_NODES) return;
    const int c = lane * 2;
    const float2 att2 = *(const float2*)(att + c);
    const float2 xr2  = *(const float2*)(xr + (size_t)i * TOT_CH + c);
    const int k0 = rowptr[i], k1 = rowptr[i + 1];

    float m = -INFINITY, den = 0.f, a0 = 0.f, a1 = 0.f;
    int k = k0;

#define SCOREU(u, sv) do { \
        const float t0 = bflo(u) + xr2.x, t1 = bfhi(u) + xr2.y; \
        const float l0 = fmaxf(t0, 0.f) + NEG_SLOPE * fminf(t0, 0.f); \
        const float l1 = fmaxf(t1, 0.f) + NEG_SLOPE * fminf(t1, 0.f); \
        sv = att2.x * l0 + att2.y * l1; } while(0)

#define RED4(a, b, cc, d) do { \
        a += __shfl_xor(a, 1); b += __shfl_xor(b, 1); cc += __shfl_xor(cc, 1); d += __shfl_xor(d, 1); \
        a += __shfl_xor(a, 2); b += __shfl_xor(b, 2); cc += __shfl_xor(cc, 2); d += __shfl_xor(d, 2); \
        a += __shfl_xor(a, 4); b += __shfl_xor(b, 4); cc += __shfl_xor(cc, 4); d += __shfl_xor(d, 4); \
        a += __shfl_xor(a, 8); b += __shfl_xor(b, 8); cc += __shfl_xor(cc, 8); d += __shfl_xor(d, 8); } while(0)

    for (; k + 8 <= k1; k += 8) {
        const int j0 = srcs[k + 0], j1 = srcs[k + 1], j2 = srcs[k + 2], j3 = srcs[k + 3];
        const int j4 = srcs[k + 4], j5 = srcs[k + 5], j6 = srcs[k + 6], j7 = srcs[k + 7];
        const unsigned u0 = xl_bf[(size_t)j0 * 64 + lane];
        const unsigned u1 = xl_bf[(size_t)j1 * 64 + lane];
        const unsigned u2 = xl_bf[(size_t)j2 * 64 + lane];
        const unsigned u3 = xl_bf[(size_t)j3 * 64 + lane];
        const unsigned u4 = xl_bf[(size_t)j4 * 64 + lane];
        const unsigned u5 = xl_bf[(size_t)j5 * 64 + lane];
        const unsigned u6 = xl_bf[(size_t)j6 * 64 + lane];
        const unsigned u7 = xl_bf[(size_t)j7 * 64 + lane];
        float s0, s1, s2, s3, s4, s5, s6, s7;
        SCOREU(u0, s0); SCOREU(u1, s1); SCOREU(u2, s2); SCOREU(u3, s3);
        SCOREU(u4, s4); SCOREU(u5, s5); SCOREU(u6, s6); SCOREU(u7, s7);
        RED4(s0, s1, s2, s3);
        RED4(s4, s5, s6, s7);
        const float mx = fmaxf(fmaxf(fmaxf(fmaxf(s0, s1), fmaxf(s2, s3)),
                                     fmaxf(fmaxf(s4, s5), fmaxf(s6, s7))), m);
        const float corr = __expf(m - mx);
        const float p0 = __expf(s0 - mx), p1 = __expf(s1 - mx);
        const float p2 = __expf(s2 - mx), p3 = __expf(s3 - mx);
        const float p4 = __expf(s4 - mx), p5 = __expf(s5 - mx);
        const float p6 = __expf(s6 - mx), p7 = __expf(s7 - mx);
        den = den * corr + (((p0 + p1) + (p2 + p3)) + ((p4 + p5) + (p6 + p7)));
        a0  = a0  * corr + (((p0 * bflo(u0) + p1 * bflo(u1)) + (p2 * bflo(u2) + p3 * bflo(u3)))
                          + ((p4 * bflo(u4) + p5 * bflo(u5)) + (p6 * bflo(u6) + p7 * bflo(u7))));
        a1  = a1  * corr + (((p0 * bfhi(u0) + p1 * bfhi(u1)) + (p2 * bfhi(u2) + p3 * bfhi(u3)))
                          + ((p4 * bfhi(u4) + p5 * bfhi(u5)) + (p6 * bfhi(u6) + p7 * bfhi(u7))));
        m = mx;
    }
    for (; k + 4 <= k1; k += 4) {
        const int j0 = srcs[k + 0], j1 = srcs[k + 1], j2 = srcs[k + 2], j3 = srcs[k + 3];
        const unsigned u0 = xl_bf[(size_t)j0 * 64 + lane];
        const unsigned u1 = xl_bf[(size_t)j1 * 64 + lane];
        const unsigned u2 = xl_bf[(size_t)j2 * 64 + lane];
        const unsigned u3 = xl_bf[(size_t)j3 * 64 + lane];
        float s0, s1, s2, s3;
        SCOREU(u0, s0); SCOREU(u1, s1); SCOREU(u2, s2); SCOREU(u3, s3);
        RED4(s0, s1, s2, s3);
        const float mx = fmaxf(fmaxf(fmaxf(s0, s1), fmaxf(s2, s3)), m);
        const float corr = __expf(m - mx);
        const float p0 = __expf(s0 - mx), p1 = __expf(s1 - mx);
        const float p2 = __expf(s2 - mx), p3 = __expf(s3 - mx);
        den = den * corr + ((p0 + p1) + (p2 + p3));
        a0  = a0  * corr + ((p0 * bflo(u0) + p1 * bflo(u1)) + (p2 * bflo(u2) + p3 * bflo(u3)));
        a1  = a1  * corr + ((p0 * bfhi(u0) + p1 * bfhi(u1)) + (p2 * bfhi(u2) + p3 * bfhi(u3)));
        m = mx;
    }
    for (; k < k1; ++k) {
        const int j = srcs[k];
        const unsigned u = xl_bf[(size_t)j * 64 + lane];
        float s;
        SCOREU(u, s);
        s += __shfl_xor(s, 1);
        s += __shfl_xor(s, 2);
        s += __shfl_xor(s, 4);
        s += __shfl_xor(s, 8);
        const float mn   = fmaxf(m, s);
        const float corr = __expf(m - mn);
        const float p    = __expf(s - mn);
        den = den * corr + p;
        a0  = a0 * corr + p * bflo(u);
        a1  = a1 * corr + p * bfhi(u);
        m = mn;
    }
    const float inv = 1.f / den;
    const float2 b2 = *(const float2*)(bias + c);
    float2 o;
    o.x = a0 * inv + b2.x;
    o.y = a1 * inv + b2.y;
    *(float2*)(out + (size_t)i * TOT_CH + c) = o;
}

// ================= launch =================
extern "C" void kernel_launch(void* const* d_in, const int* in_sizes, int n_in,
                              void* d_out, int out_size, void* d_ws, size_t ws_size,
                              hipStream_t stream) {
    const float* x    = (const float*)d_in[0];
    const int*   ei   = (const int*)d_in[1];
    const float* Wl   = (const float*)d_in[2];
    const float* Wr   = (const float*)d_in[3];
    const float* att  = (const float*)d_in[4];
    const float* bias = (const float*)d_in[5];
    float* out = (float*)d_out;
    char*  ws  = (char*)d_ws;

    unsigned* xl_bf = (unsigned*)(ws + OFF_XL);
    uint2*    ebuf  = (uint2*)(ws + OFF_EBUF);
    float*    xr    = (float*)(ws + OFF_XR);
    int*   rowptr = (int*)(ws + OFF_ROWPTR);
    unsigned* btg = (unsigned*)(ws + OFF_BT);
    int*   ssrc   = (int*)(ws + OFF_SRC);
    int*   gcnt   = (int*)(ws + OFF_GCNT);
    int*   bstart = (int*)(ws + OFF_BSTART);
    int*   gcur   = (int*)(ws + OFF_GCUR);

    hipLaunchKernelGGL(wconv_kernel, dim3(64), dim3(256), 0, stream, Wl, Wr, btg, gcnt);
    hipLaunchKernelGGL(gemm_kernel, dim3(MTILES * 4), dim3(256), 0, stream,
                       x, btg, xl_bf, xr);
    hipLaunchKernelGGL(binA_kernel, dim3(NBIN), dim3(256), 0, stream, ei, gcnt);
    hipLaunchKernelGGL(scanB_kernel, dim3(1), dim3(256), 0, stream, gcnt, bstart, gcur, rowptr);
    hipLaunchKernelGGL(binscatter_kernel, dim3(NBIN), dim3(256), 0, stream, ei, gcur, ebuf);
    hipLaunchKernelGGL(place_kernel, dim3(NBUCK), dim3(512), 0, stream,
                       ebuf, gcnt, bstart, rowptr, ssrc);
    hipLaunchKernelGGL(gat_kernel, dim3((N_NODES + 3) / 4), dim3(256), 0, stream,
                       xl_bf, xr, rowptr, ssrc, att, bias, out);
}

// Round 8
// 118.199 us; speedup vs baseline: 2.7017x; 1.0115x over previous
//
#include <hip/hip_runtime.h>
#include <math.h>

#define N_NODES 50000
#define IN_CH   128
#define TOT_CH  128          // HEADS*OUT_CH
#define NEDGE   800000
#define ETOT    (NEDGE + N_NODES)
#define NEG_SLOPE 0.2f
#define MTILES  ((N_NODES + 63) / 64)     // 782
#define BUCK_SHIFT 8
#define NBUCK   ((N_NODES + 255) / 256)   // 196 buckets of 256 nodes
#define EPB     4096                       // edges per binning block
#define NBIN    ((ETOT + EPB - 1) / EPB)   // 208

// ---------------- workspace layout (bytes) ----------------
#define OFF_XL      ((size_t)0)                 // bf16 [N][128] = 12.8MB
#define OFF_EBUF    ((size_t)12800000)          // uint2 [ETOT] = 6.8MB
#define OFF_XR      ((size_t)25600000)          // f32  [N][128] = 25.6MB
#define OFF_ROWPTR  ((size_t)51200000)          // (N+1)*4
#define OFF_BT      ((size_t)51400064)          // Bt bf16-pairs 64KB
#define OFF_SRC     ((size_t)51800064)          // ETOT*4 = 3.4MB
#define OFF_GCNT    ((size_t)55200064)
#define OFF_BSTART  ((size_t)55201088)
#define OFF_GCUR    ((size_t)55202112)

typedef float f32x4 __attribute__((ext_vector_type(4)));
typedef short s16x8 __attribute__((ext_vector_type(8)));

__device__ __forceinline__ unsigned f2bf(float f) {   // RNE f32->bf16 bits
    unsigned u = __float_as_uint(f);
    return (u + 0x7fffu + ((u >> 16) & 1u)) >> 16;
}
__device__ __forceinline__ float bflo(unsigned u) { return __uint_as_float(u << 16); }
__device__ __forceinline__ float bfhi(unsigned u) { return __uint_as_float(u & 0xffff0000u); }

__device__ __forceinline__ int SWZ(int row, int byteoff) {
    return row * 256 + (byteoff ^ ((row & 7) << 4));
}

// ============ W conversion + gcnt zero ============
__global__ __launch_bounds__(256) void wconv_kernel(
    const float* __restrict__ Wl, const float* __restrict__ Wr,
    unsigned* __restrict__ btg, int* __restrict__ gcnt)
{
    const int g = blockIdx.x * 256 + threadIdx.x;
    if (g < NBUCK) gcnt[g] = 0;
    if (g >= 256 * 64) return;
    const int n = g >> 6, kk = g & 63;
    const float* W = (n < 128) ? Wl : Wr;
    const int nc = n & 127;
    const float a = W[(size_t)(2 * kk) * 128 + nc];
    const float b = W[(size_t)(2 * kk + 1) * 128 + nc];
    btg[g] = f2bf(a) | (f2bf(b) << 16);
}

// ============ MFMA GEMM: x[N,128](f32->bf16) @ Bt -> xl(bf16), xr(f32) ============
__global__ __launch_bounds__(256) void gemm_kernel(
    const float* __restrict__ x, const unsigned* __restrict__ btg,
    unsigned* __restrict__ xl_bf, float* __restrict__ xr)
{
    __shared__ __align__(16) unsigned char Al[64 * 256];
    __shared__ __align__(16) unsigned char Bl[64 * 256];

    const int t  = threadIdx.x;
    const int nt = blockIdx.x / MTILES;
    const int mt = blockIdx.x % MTILES;
    const int mbase = mt * 64;
    const int nbase = nt * 64;

    {
        const int r = t >> 2, q = t & 3;
        int gm = mbase + r;
        gm = (gm < N_NODES) ? gm : (N_NODES - 1);
        const float* xrow = x + (size_t)gm * IN_CH + q * 32;
#pragma unroll
        for (int i = 0; i < 8; ++i) {
            const float4 xv = *(const float4*)(xrow + i * 4);
            uint2 p;
            p.x = f2bf(xv.x) | (f2bf(xv.y) << 16);
            p.y = f2bf(xv.z) | (f2bf(xv.w) << 16);
            *(uint2*)(Al + SWZ(r, q * 64 + i * 8)) = p;
        }
    }
    {
        const int r = t >> 2, q = t & 3;
        const unsigned* brow = btg + (size_t)(nbase + r) * 64 + q * 16;
#pragma unroll
        for (int i = 0; i < 4; ++i) {
            const uint4 v = *(const uint4*)(brow + i * 4);
            *(uint4*)(Bl + SWZ(r, q * 64 + i * 16)) = v;
        }
    }
    __syncthreads();

    const int l  = t & 63;
    const int wv = t >> 6;

    f32x4 acc[4];
#pragma unroll
    for (int n = 0; n < 4; ++n) acc[n] = (f32x4){0.f, 0.f, 0.f, 0.f};

    s16x8 af[4];
#pragma unroll
    for (int ks = 0; ks < 4; ++ks)
        af[ks] = *(const s16x8*)(Al + SWZ(wv * 16 + (l & 15), ks * 64 + (l >> 4) * 16));

#pragma unroll
    for (int nsub = 0; nsub < 4; ++nsub) {
#pragma unroll
        for (int ks = 0; ks < 4; ++ks) {
            const s16x8 bfr = *(const s16x8*)(Bl + SWZ(nsub * 16 + (l & 15), ks * 64 + (l >> 4) * 16));
            acc[nsub] = __builtin_amdgcn_mfma_f32_16x16x32_bf16(af[ks], bfr, acc[nsub], 0, 0, 0);
        }
    }

    if (nt < 2) {
#pragma unroll
        for (int nsub = 0; nsub < 4; ++nsub) {
            const int n = nt * 64 + nsub * 16 + (l & 15);
#pragma unroll
            for (int reg = 0; reg < 4; ++reg) {
                const float v  = acc[nsub][reg];
                const float vp = __shfl_xor(v, 1);
                const int row = mbase + wv * 16 + (l >> 4) * 4 + reg;
                if (((l & 1) == 0) && row < N_NODES)
                    xl_bf[(size_t)row * 64 + (n >> 1)] = f2bf(v) | (f2bf(vp) << 16);
            }
        }
    } else {
#pragma unroll
        for (int nsub = 0; nsub < 4; ++nsub) {
            const int cx = (nt - 2) * 64 + nsub * 16 + (l & 15);
#pragma unroll
            for (int reg = 0; reg < 4; ++reg) {
                const int row = mbase + wv * 16 + (l >> 4) * 4 + reg;
                if (row < N_NODES)
                    xr[(size_t)row * TOT_CH + cx] = acc[nsub][reg];
            }
        }
    }
}

// ================= CSR build via bucketed counting sort =================
__global__ __launch_bounds__(256) void binA_kernel(
    const int* __restrict__ ei, int* __restrict__ gcnt)
{
    __shared__ int lcnt[NBUCK];
    for (int i = threadIdx.x; i < NBUCK; i += 256) lcnt[i] = 0;
    __syncthreads();
    const int base = blockIdx.x * EPB;
#pragma unroll
    for (int u = 0; u < 16; ++u) {
        const int e = base + u * 256 + threadIdx.x;
        if (e < ETOT) {
            const int dst = (e < NEDGE) ? ei[NEDGE + e] : (e - NEDGE);
            atomicAdd(&lcnt[dst >> BUCK_SHIFT], 1);
        }
    }
    __syncthreads();
    for (int i = threadIdx.x; i < NBUCK; i += 256) {
        const int v = lcnt[i];
        if (v) atomicAdd(&gcnt[i], v);
    }
}

__global__ __launch_bounds__(256) void scanB_kernel(
    const int* __restrict__ gcnt, int* __restrict__ bstart,
    int* __restrict__ gcursor, int* __restrict__ rowptr)
{
    __shared__ int wsum[4];
    const int tid = threadIdx.x, lane = tid & 63, wid = tid >> 6;
    const int v = (tid < NBUCK) ? gcnt[tid] : 0;
    int s = v;
#pragma unroll
    for (int off = 1; off < 64; off <<= 1) {
        int t = __shfl_up(s, off);
        if (lane >= off) s += t;
    }
    if (lane == 63) wsum[wid] = s;
    __syncthreads();
    if (tid == 0) {
        int acc = 0;
#pragma unroll
        for (int w = 0; w < 4; ++w) { int t = wsum[w]; wsum[w] = acc; acc += t; }
    }
    __syncthreads();
    if (tid < NBUCK) {
        const int e = wsum[wid] + s - v;
        bstart[tid] = e;
        gcursor[tid] = e;
    }
    if (tid == 0) rowptr[N_NODES] = ETOT;
}

__global__ __launch_bounds__(256) void binscatter_kernel(
    const int* __restrict__ ei, int* __restrict__ gcursor, uint2* __restrict__ ebuf)
{
    __shared__ int lcnt[NBUCK];
    __shared__ int lbase[NBUCK];
    for (int i = threadIdx.x; i < NBUCK; i += 256) lcnt[i] = 0;
    __syncthreads();
    const int base = blockIdx.x * EPB;
    int srcv[16], dstv[16];
#pragma unroll
    for (int u = 0; u < 16; ++u) {
        const int e = base + u * 256 + threadIdx.x;
        int s32 = 0, d32 = -1;
        if (e < ETOT) {
            if (e < NEDGE) { s32 = ei[e]; d32 = ei[NEDGE + e]; }
            else           { s32 = d32 = e - NEDGE; }
            atomicAdd(&lcnt[d32 >> BUCK_SHIFT], 1);
        }
        srcv[u] = s32; dstv[u] = d32;
    }
    __syncthreads();
    for (int i = threadIdx.x; i < NBUCK; i += 256) {
        const int v = lcnt[i];
        lbase[i] = v ? atomicAdd(&gcursor[i], v) : 0;
    }
    __syncthreads();
    for (int i = threadIdx.x; i < NBUCK; i += 256) lcnt[i] = 0;
    __syncthreads();
#pragma unroll
    for (int u = 0; u < 16; ++u) {
        const int d32 = dstv[u];
        if (d32 >= 0) {
            const int b = d32 >> BUCK_SHIFT;
            const int p = lbase[b] + atomicAdd(&lcnt[b], 1);
            ebuf[p] = make_uint2((unsigned)srcv[u], (unsigned)d32);
        }
    }
}

__global__ __launch_bounds__(512) void place_kernel(
    const uint2* __restrict__ ebuf, const int* __restrict__ gcnt,
    const int* __restrict__ bstart, int* __restrict__ rowptr, int* __restrict__ ssrc)
{
    __shared__ int lcnt[256];
    __shared__ int wsum[4];
    const int b = blockIdx.x;
    const int node0 = b << BUCK_SHIFT;
    const int estart = bstart[b];
    const int ecnt = gcnt[b];
    const int tid = threadIdx.x, lane = tid & 63, wid = tid >> 6;
    if (tid < 256) lcnt[tid] = 0;
    __syncthreads();
    for (int k = tid; k < ecnt; k += 512) {
        const uint2 ed = ebuf[estart + k];
        atomicAdd(&lcnt[ed.y & 255], 1);
    }
    __syncthreads();
    int v = 0, s = 0;
    if (tid < 256) {
        v = lcnt[tid];
        s = v;
#pragma unroll
        for (int off = 1; off < 64; off <<= 1) {
            int t = __shfl_up(s, off);
            if (lane >= off) s += t;
        }
        if (lane == 63) wsum[wid] = s;
    }
    __syncthreads();
    if (tid == 0) {
        int acc = 0;
#pragma unroll
        for (int w = 0; w < 4; ++w) { int t = wsum[w]; wsum[w] = acc; acc += t; }
    }
    __syncthreads();
    if (tid < 256) {
        const int gpos = estart + wsum[wid] + s - v;
        const int node = node0 + tid;
        if (node < N_NODES) rowptr[node] = gpos;
        lcnt[tid] = gpos;
    }
    __syncthreads();
    for (int k = tid; k < ecnt; k += 512) {
        const uint2 ed = ebuf[estart + k];
        const int p = atomicAdd(&lcnt[ed.y & 255], 1);
        ssrc[p] = (int)ed.x;
    }
}

// ================= fused attention + aggregate: one wave per dst node =========
// score via leaky(t)=0.6t+0.4|t| -> 4 fma w/ abs modifiers; aggregate via
// b = sum(p*t), out = b/den - xr + bias; SGPR-base gathers; exact defer-rescale.
__global__ __launch_bounds__(256) void gat_kernel(
    const unsigned* __restrict__ xl_bf, const float* __restrict__ xr,
    const int* __restrict__ rowptr, const int* __restrict__ srcs,
    const float* __restrict__ att, const float* __restrict__ bias,
    float* __restrict__ out)
{
    const int lane = threadIdx.x & 63;
    const int i = blockIdx.x * 4 + (threadIdx.x >> 6);
    if (i >= N_NODES) return;
    const int c = lane * 2;
    const float2 att2 = *(const float2*)(att + c);
    const float2 xr2  = *(const float2*)(xr + (size_t)i * TOT_CH + c);
    const float a6x = 0.6f * att2.x, a4x = 0.4f * att2.x;
    const float a6y = 0.6f * att2.y, a4y = 0.4f * att2.y;
    const int k0 = rowptr[i], k1 = rowptr[i + 1];

    float m = -INFINITY, den = 0.f, b0 = 0.f, b1 = 0.f;
    int k = k0;

#define LOADU(n, kk) \
    const int j##n = __builtin_amdgcn_readfirstlane(srcs[kk]); \
    const unsigned u##n = *(xl_bf + (size_t)j##n * 64 + lane);

#define SCORE(n) \
    const float t0_##n = bflo(u##n) + xr2.x; \
    const float t1_##n = bfhi(u##n) + xr2.y; \
    float s##n = fmaf(a6x, t0_##n, fmaf(a4x, fabsf(t0_##n), \
                 fmaf(a6y, t1_##n, a4y * fabsf(t1_##n))));

#define RED4(a, b, cc, d) do { \
        a += __shfl_xor(a, 1); b += __shfl_xor(b, 1); cc += __shfl_xor(cc, 1); d += __shfl_xor(d, 1); \
        a += __shfl_xor(a, 2); b += __shfl_xor(b, 2); cc += __shfl_xor(cc, 2); d += __shfl_xor(d, 2); \
        a += __shfl_xor(a, 4); b += __shfl_xor(b, 4); cc += __shfl_xor(cc, 4); d += __shfl_xor(d, 4); \
        a += __shfl_xor(a, 8); b += __shfl_xor(b, 8); cc += __shfl_xor(cc, 8); d += __shfl_xor(d, 8); } while(0)

    for (; k + 8 <= k1; k += 8) {
        LOADU(0, k + 0); LOADU(1, k + 1); LOADU(2, k + 2); LOADU(3, k + 3);
        LOADU(4, k + 4); LOADU(5, k + 5); LOADU(6, k + 6); LOADU(7, k + 7);
        SCORE(0); SCORE(1); SCORE(2); SCORE(3);
        SCORE(4); SCORE(5); SCORE(6); SCORE(7);
        RED4(s0, s1, s2, s3);
        RED4(s4, s5, s6, s7);
        const float mx = fmaxf(fmaxf(fmaxf(s0, s1), fmaxf(s2, s3)),
                               fmaxf(fmaxf(s4, s5), fmaxf(s6, s7)));
        if (__any(mx > m)) {
            const float mn = fmaxf(mx, m);
            const float corr = (m == -INFINITY) ? 0.f : __expf(m - mn);
            den *= corr; b0 *= corr; b1 *= corr;
            m = mn;
        }
        const float p0 = __expf(s0 - m), p1 = __expf(s1 - m);
        const float p2 = __expf(s2 - m), p3 = __expf(s3 - m);
        const float p4 = __expf(s4 - m), p5 = __expf(s5 - m);
        const float p6 = __expf(s6 - m), p7 = __expf(s7 - m);
        den += ((p0 + p1) + (p2 + p3)) + ((p4 + p5) + (p6 + p7));
        b0 = fmaf(p0, t0_0, fmaf(p1, t0_1, fmaf(p2, t0_2, fmaf(p3, t0_3,
             fmaf(p4, t0_4, fmaf(p5, t0_5, fmaf(p6, t0_6, fmaf(p7, t0_7, b0))))))));
        b1 = fmaf(p0, t1_0, fmaf(p1, t1_1, fmaf(p2, t1_2, fmaf(p3, t1_3,
             fmaf(p4, t1_4, fmaf(p5, t1_5, fmaf(p6, t1_6, fmaf(p7, t1_7, b1))))))));
    }
    if (k + 4 <= k1) {
        LOADU(0, k + 0); LOADU(1, k + 1); LOADU(2, k + 2); LOADU(3, k + 3);
        SCORE(0); SCORE(1); SCORE(2); SCORE(3);
        RED4(s0, s1, s2, s3);
        const float mx = fmaxf(fmaxf(s0, s1), fmaxf(s2, s3));
        if (__any(mx > m)) {
            const float mn = fmaxf(mx, m);
            const float corr = (m == -INFINITY) ? 0.f : __expf(m - mn);
            den *= corr; b0 *= corr; b1 *= corr;
            m = mn;
        }
        const float p0 = __expf(s0 - m), p1 = __expf(s1 - m);
        const float p2 = __expf(s2 - m), p3 = __expf(s3 - m);
        den += (p0 + p1) + (p2 + p3);
        b0 = fmaf(p0, t0_0, fmaf(p1, t0_1, fmaf(p2, t0_2, fmaf(p3, t0_3, b0))));
        b1 = fmaf(p0, t1_0, fmaf(p1, t1_1, fmaf(p2, t1_2, fmaf(p3, t1_3, b1))));
        k += 4;
    }
    for (; k < k1; ++k) {
        LOADU(9, k);
        SCORE(9);
        s9 += __shfl_xor(s9, 1);
        s9 += __shfl_xor(s9, 2);
        s9 += __shfl_xor(s9, 4);
        s9 += __shfl_xor(s9, 8);
        if (__any(s9 > m)) {
            const float mn = fmaxf(s9, m);
            const float corr = (m == -INFINITY) ? 0.f : __expf(m - mn);
            den *= corr; b0 *= corr; b1 *= corr;
            m = mn;
        }
        const float p = __expf(s9 - m);
        den += p;
        b0 = fmaf(p, t0_9, b0);
        b1 = fmaf(p, t1_9, b1);
    }
    const float inv = 1.f / den;
    const float2 bb = *(const float2*)(bias + c);
    float2 o;
    o.x = fmaf(b0, inv, bb.x - xr2.x);
    o.y = fmaf(b1, inv, bb.y - xr2.y);
    *(float2*)(out + (size_t)i * TOT_CH + c) = o;
}

// ================= launch =================
extern "C" void kernel_launch(void* const* d_in, const int* in_sizes, int n_in,
                              void* d_out, int out_size, void* d_ws, size_t ws_size,
                              hipStream_t stream) {
    const float* x    = (const float*)d_in[0];
    const int*   ei   = (const int*)d_in[1];
    const float* Wl   = (const float*)d_in[2];
    const float* Wr   = (const float*)d_in[3];
    const float* att  = (const float*)d_in[4];
    const float* bias = (const float*)d_in[5];
    float* out = (float*)d_out;
    char*  ws  = (char*)d_ws;

    unsigned* xl_bf = (unsigned*)(ws + OFF_XL);
    uint2*    ebuf  = (uint2*)(ws + OFF_EBUF);
    float*    xr    = (float*)(ws + OFF_XR);
    int*   rowptr = (int*)(ws + OFF_ROWPTR);
    unsigned* btg = (unsigned*)(ws + OFF_BT);
    int*   ssrc   = (int*)(ws + OFF_SRC);
    int*   gcnt   = (int*)(ws + OFF_GCNT);
    int*   bstart = (int*)(ws + OFF_BSTART);
    int*   gcur   = (int*)(ws + OFF_GCUR);

    hipLaunchKernelGGL(wconv_kernel, dim3(64), dim3(256), 0, stream, Wl, Wr, btg, gcnt);
    hipLaunchKernelGGL(gemm_kernel, dim3(MTILES * 4), dim3(256), 0, stream,
                       x, btg, xl_bf, xr);
    hipLaunchKernelGGL(binA_kernel, dim3(NBIN), dim3(256), 0, stream, ei, gcnt);
    hipLaunchKernelGGL(scanB_kernel, dim3(1), dim3(256), 0, stream, gcnt, bstart, gcur, rowptr);
    hipLaunchKernelGGL(binscatter_kernel, dim3(NBIN), dim3(256), 0, stream, ei, gcur, ebuf);
    hipLaunchKernelGGL(place_kernel, dim3(NBUCK), dim3(512), 0, stream,
                       ebuf, gcnt, bstart, rowptr, ssrc);
    hipLaunchKernelGGL(gat_kernel, dim3((N_NODES + 3) / 4), dim3(256), 0, stream,
                       xl_bf, xr, rowptr, ssrc, att, bias, out);
}